// Round 3
// baseline (793.379 us; speedup 1.0000x reference)
//
#include <hip/hip_runtime.h>
#include <math.h>

// Geometry (fixed): B=16, C=1, H=W=1024, f32.
#define H_IMG 1024
#define W_IMG 1024
#define N_B   16
#define NPIX  (H_IMG * W_IMG)
#define N_TOT (16LL * NPIX)

// 64x64 owned tile, halo 12 (11 fused erode iters + 1 dilate ring).
#define TILE 64
#define HALO 12
#define RG   88          // TILE + 2*HALO rows / data cols
#define RST  92          // LDS row stride (floats) = 23 float4 strips (22 data + 1 pad)
#define SLOTS 32         // atomic accumulator slots (each its own 64B line)

__device__ __forceinline__ float sigm(float x)  { return 1.0f / (1.0f + __expf(-x)); }
__device__ __forceinline__ float min3f(float a, float b, float c) { return fminf(fminf(a, b), c); }
__device__ __forceinline__ float max3f(float a, float b, float c) { return fmaxf(fmaxf(a, b), c); }

// Overwrite region cells whose GLOBAL coords are outside the image with +INF
// (erode-input identity). Stride-1 b32 writes: conflict-free.
__device__ __forceinline__ void band_fix_inf(float* b, int r0, int c0, int tid)
{
    const float val = __builtin_inff();
    if (r0 == 0) {
        for (int idx = tid; idx < HALO * RG; idx += 512) {
            const int r = idx / RG, c = idx - r * RG;
            b[r * RST + c] = val;
        }
    }
    if (r0 == H_IMG - TILE) {
        for (int idx = tid; idx < HALO * RG; idx += 512) {
            const int r = idx / RG, c = idx - r * RG;
            b[(RG - HALO + r) * RST + c] = val;
        }
    }
    if (c0 == 0) {
        for (int idx = tid; idx < RG * HALO; idx += 512) {
            const int r = idx / HALO, c = idx - r * HALO;
            b[r * RST + c] = val;
        }
    }
    if (c0 == W_IMG - TILE) {
        for (int idx = tid; idx < RG * HALO; idx += 512) {
            const int r = idx / HALO, c = idx - r * HALO;
            b[r * RST + (RG - HALO + c)] = val;
        }
    }
}

// ---------------------------------------------------------------------------
// Whole soft_skeleton (11 iters) for one 64x64 tile in LDS, plus fused
// reductions: always sum(skel), sum(skel*other); DO_BCE adds BCE + dice sums
// (reloading pred logits for owned pixels from global — L3-hot).
// Bank-conflict design: every LDS b128 phase has quarter-wave = {1 row x 16
// consecutive strips} or {2 rows x 8 consecutive strips} -> <=2 lanes/bank.
// Validity: after erode k, nxt valid on region margin >= k+1; strip-trimmed
// range [sA,sE) always covers the dilate ring and the tight k==3 mod 4
// boundary strip is freshly written at k-1.
// ---------------------------------------------------------------------------
template<bool SIG_SRC, bool SIG_OTH, bool DO_BCE, int CBASE>
__device__ __forceinline__
void skel_core(const float* __restrict__ src, const float* __restrict__ oth,
               double* __restrict__ acc, float* cur, float* nxt, float* red,
               int z, int r0, int c0, int tid, int bid)
{
    const float* s = src + (size_t)z * NPIX;

    // ---- load 88x88 region (+4-col pad), phase-aligned ----
    {   // phase A: strips 0..15, quarter-wave = 1 row x 16 strips
        const int st = tid & 15, c = 4 * st;
        const int gc = c0 - HALO + c;
        const bool vec = (gc >= 0) && (gc + 3 < W_IMG);
        for (int r = tid >> 4; r < RG; r += 32) {
            const int gr = min(max(r0 - HALO + r, 0), H_IMG - 1);
            const float* row = s + (size_t)gr * W_IMG;
            float4 v;
            if (vec) v = *(const float4*)&row[gc];
            else {
                v.x = row[min(max(gc + 0, 0), W_IMG - 1)];
                v.y = row[min(max(gc + 1, 0), W_IMG - 1)];
                v.z = row[min(max(gc + 2, 0), W_IMG - 1)];
                v.w = row[min(max(gc + 3, 0), W_IMG - 1)];
            }
            if (SIG_SRC) { v.x = sigm(v.x); v.y = sigm(v.y); v.z = sigm(v.z); v.w = sigm(v.w); }
            *(float4*)&cur[r * RST + c] = v;
        }
    }
    {   // phase B: strips 16..22 (incl pad strip 22), 2 rows x 8 strips/quarter
        const int st = 16 + (tid & 7);
        if (st < 23) {
            const int c = 4 * st, gc = c0 - HALO + c;
            const bool vec = (gc >= 0) && (gc + 3 < W_IMG);
            for (int r = tid >> 3; r < RG; r += 64) {
                const int gr = min(max(r0 - HALO + r, 0), H_IMG - 1);
                const float* row = s + (size_t)gr * W_IMG;
                float4 v;
                if (vec) v = *(const float4*)&row[gc];
                else {
                    v.x = row[min(max(gc + 0, 0), W_IMG - 1)];
                    v.y = row[min(max(gc + 1, 0), W_IMG - 1)];
                    v.z = row[min(max(gc + 2, 0), W_IMG - 1)];
                    v.w = row[min(max(gc + 3, 0), W_IMG - 1)];
                }
                if (SIG_SRC) { v.x = sigm(v.x); v.y = sigm(v.y); v.z = sigm(v.z); v.w = sigm(v.w); }
                *(float4*)&cur[r * RST + c] = v;
            }
        }
    }
    __syncthreads();

    const bool edge = (r0 == 0) | (c0 == 0) | (r0 == H_IMG - TILE) | (c0 == W_IMG - TILE);
    const float NINF = -__builtin_inff();

    float4 sk[2];
    sk[0] = make_float4(0.f, 0.f, 0.f, 0.f);
    sk[1] = make_float4(0.f, 0.f, 0.f, 0.f);

    const int oy = tid >> 3;      // owned row 0..63
    const int j  = tid & 7;       // strip slot (strips j, j+8 of owned)
    const int rr = HALO + oy;

    for (int k = 0; k < 11; ++k) {
        if (edge) { band_fix_inf(cur, r0, c0, tid); __syncthreads(); }

        const int rlo = k + 1, rhi = RG - 1 - k;        // rows [rlo, rhi)
        const int sA = rlo >> 2, sE = (rhi + 3) >> 2;   // strips [sA, sE)

        // ---- erode phase A: strips sA..sA+15 (quarter = 1 row x 16 strips) ----
        {
            const int st = sA + (tid & 15), c = 4 * st;
            const int gcb = c0 - HALO + c;
            const bool cOOB = ((unsigned)gcb > (unsigned)(W_IMG - 4));
            for (int r = rlo + (tid >> 4); r < rhi; r += 32) {
                const int base = r * RST + c;
                const float4 mid = *(const float4*)&cur[base];
                const float4 up  = *(const float4*)&cur[base - RST];
                const float4 dn  = *(const float4*)&cur[base + RST];
                const float  lf  = cur[base - 1];
                const float  rt  = cur[base + 4];
                float4 e;
                e.x = min3f(min3f(up.x, mid.x, dn.x), lf,    mid.y);
                e.y = min3f(min3f(up.y, mid.y, dn.y), mid.x, mid.z);
                e.z = min3f(min3f(up.z, mid.z, dn.z), mid.y, mid.w);
                e.w = min3f(min3f(up.w, mid.w, dn.w), mid.z, rt);
                if (edge) {
                    const int gr = r0 - HALO + r;
                    if (((unsigned)gr >= (unsigned)H_IMG) | cOOB) { e.x = e.y = e.z = e.w = NINF; }
                }
                *(float4*)&nxt[base] = e;
            }
        }
        // ---- erode phase B: strips sA+16..sE-1 (quarter = 2 rows x 8 strips) ----
        {
            const int st = sA + 16 + (tid & 7);
            if (st < sE) {
                const int c = 4 * st;
                const int gcb = c0 - HALO + c;
                const bool cOOB = ((unsigned)gcb > (unsigned)(W_IMG - 4));
                for (int r = rlo + (tid >> 3); r < rhi; r += 64) {
                    const int base = r * RST + c;
                    const float4 mid = *(const float4*)&cur[base];
                    const float4 up  = *(const float4*)&cur[base - RST];
                    const float4 dn  = *(const float4*)&cur[base + RST];
                    const float  lf  = cur[base - 1];
                    const float  rt  = cur[base + 4];
                    float4 e;
                    e.x = min3f(min3f(up.x, mid.x, dn.x), lf,    mid.y);
                    e.y = min3f(min3f(up.y, mid.y, dn.y), mid.x, mid.z);
                    e.z = min3f(min3f(up.z, mid.z, dn.z), mid.y, mid.w);
                    e.w = min3f(min3f(up.w, mid.w, dn.w), mid.z, rt);
                    if (edge) {
                        const int gr = r0 - HALO + r;
                        if (((unsigned)gr >= (unsigned)H_IMG) | cOOB) { e.x = e.y = e.z = e.w = NINF; }
                    }
                    *(float4*)&nxt[base] = e;
                }
            }
        }
        __syncthreads();

        // ---- dilate(ernew) at owned pixels + skel update ----
        #pragma unroll
        for (int t = 0; t < 2; ++t) {
            const int c = HALO + 4 * (j + 8 * t);
            const int bbase = rr * RST + c;
            const float4 a = *(const float4*)&nxt[bbase - RST];
            const float4 b = *(const float4*)&nxt[bbase];
            const float4 d = *(const float4*)&nxt[bbase + RST];
            const float aL = nxt[bbase - RST - 1], bL = nxt[bbase - 1], dL = nxt[bbase + RST - 1];
            const float aR = nxt[bbase - RST + 4], bR = nxt[bbase + 4], dR = nxt[bbase + RST + 4];
            const float vl = max3f(aL, bL, dL);
            const float v0 = max3f(a.x, b.x, d.x);
            const float v1 = max3f(a.y, b.y, d.y);
            const float v2 = max3f(a.z, b.z, d.z);
            const float v3 = max3f(a.w, b.w, d.w);
            const float vr = max3f(aR, bR, dR);
            const float4 e = *(const float4*)&cur[bbase];   // er_k at owned
            const float o0 = max3f(vl, v0, v1);
            const float o1 = max3f(v0, v1, v2);
            const float o2 = max3f(v1, v2, v3);
            const float o3 = max3f(v2, v3, vr);
            float dd;
            dd = fmaxf(e.x - o0, 0.f); sk[t].x += fmaxf(dd - sk[t].x * dd, 0.f);
            dd = fmaxf(e.y - o1, 0.f); sk[t].y += fmaxf(dd - sk[t].y * dd, 0.f);
            dd = fmaxf(e.z - o2, 0.f); sk[t].z += fmaxf(dd - sk[t].z * dd, 0.f);
            dd = fmaxf(e.w - o3, 0.f); sk[t].w += fmaxf(dd - sk[t].w * dd, 0.f);
        }
        __syncthreads();

        float* tp = cur; cur = nxt; nxt = tp;
    }

    // ---- fused reductions over owned pixels ----
    const size_t gbase = (size_t)z * NPIX + (size_t)(r0 + oy) * W_IMG + c0;
    const float* op = oth + gbase;
    const float* pp = src + gbase;   // pred logits (DO_BCE only)
    float ss = 0.f, sso = 0.f, sb = 0.f, sp = 0.f, sy = 0.f, spy = 0.f;
    #pragma unroll
    for (int t = 0; t < 2; ++t) {
        const int cc = 4 * (j + 8 * t);
        float4 ov = *(const float4*)&op[cc];
        float o0 = ov.x, o1 = ov.y, o2 = ov.z, o3 = ov.w;
        if (SIG_OTH) { o0 = sigm(o0); o1 = sigm(o1); o2 = sigm(o2); o3 = sigm(o3); }
        ss  += sk[t].x + sk[t].y + sk[t].z + sk[t].w;
        sso += sk[t].x * o0 + sk[t].y * o1 + sk[t].z * o2 + sk[t].w * o3;
        if (DO_BCE) {
            const float4 xv = *(const float4*)&pp[cc];
            const float xs[4] = {xv.x, xv.y, xv.z, xv.w};
            const float ys[4] = {o0, o1, o2, o3};   // SIG_OTH=false here: raw target
            #pragma unroll
            for (int q = 0; q < 4; ++q) {
                const float x = xs[q], y = ys[q];
                const float zz = __expf(-fabsf(x));
                const float inv = 1.0f / (1.0f + zz);
                sb += fmaxf(x, 0.f) + __logf(1.0f + zz) - y * x;
                const float p = (x >= 0.f) ? inv : zz * inv;
                sp += p; sy += y; spy += p * y;
            }
        }
    }
    for (int off = 32; off > 0; off >>= 1) {
        ss  += __shfl_down(ss,  off);
        sso += __shfl_down(sso, off);
        if (DO_BCE) {
            sb  += __shfl_down(sb,  off);
            sp  += __shfl_down(sp,  off);
            sy  += __shfl_down(sy,  off);
            spy += __shfl_down(spy, off);
        }
    }
    const int wid = tid >> 6, lane = tid & 63;
    if (lane == 0) {
        red[0 * 8 + wid] = ss;  red[1 * 8 + wid] = sso;
        if (DO_BCE) {
            red[2 * 8 + wid] = sb;  red[3 * 8 + wid] = sp;
            red[4 * 8 + wid] = sy;  red[5 * 8 + wid] = spy;
        }
    }
    __syncthreads();
    if (tid == 0) {
        double SS = 0, SO = 0, B0 = 0, B1 = 0, B2 = 0, B3 = 0;
        for (int w = 0; w < 8; ++w) {
            SS += (double)red[0 * 8 + w];  SO += (double)red[1 * 8 + w];
            if (DO_BCE) {
                B0 += (double)red[2 * 8 + w]; B1 += (double)red[3 * 8 + w];
                B2 += (double)red[4 * 8 + w]; B3 += (double)red[5 * 8 + w];
            }
        }
        const int slot = bid & (SLOTS - 1);
        atomicAdd(&acc[slot * 8 + CBASE],     SS);
        atomicAdd(&acc[slot * 8 + CBASE + 1], SO);
        if (DO_BCE) {
            atomicAdd(&acc[slot * 8 + 0], B0);
            atomicAdd(&acc[slot * 8 + 1], B1);
            atomicAdd(&acc[slot * 8 + 2], B2);
            atomicAdd(&acc[slot * 8 + 3], B3);
        }
    }
}

// Both skeletons in one dispatch: z<16 -> skel(sigmoid(pred)) + BCE/dice sums;
// z>=16 -> skel(target), reduced against sigmoid(pred).
__global__ __launch_bounds__(512, 4)
void skel_all(const float* __restrict__ pred, const float* __restrict__ tgt,
              double* __restrict__ acc)
{
    __shared__ __align__(16) float buf0[RG * RST];
    __shared__ __align__(16) float buf1[RG * RST];
    __shared__ float red[48];
    const int tid = threadIdx.x;
    const int r0 = blockIdx.y * TILE, c0 = blockIdx.x * TILE;
    const int bid = ((int)blockIdx.z & 15) * 256 + blockIdx.y * 16 + blockIdx.x;
    if ((int)blockIdx.z < N_B)
        skel_core<true,  false, true,  4>(pred, tgt, acc, buf0, buf1, red,
                                          blockIdx.z, r0, c0, tid, bid);
    else
        skel_core<false, true,  false, 6>(tgt, pred, acc, buf0, buf1, red,
                                          blockIdx.z - N_B, r0, c0, tid, bid);
}

__global__ void zero_acc(double* acc) { acc[threadIdx.x] = 0.0; }

__global__ void finalize_k(const double* __restrict__ acc, float* __restrict__ out)
{
    __shared__ double S[8];
    const int jj = threadIdx.x;
    if (jj < 8) {
        double t = 0.0;
        for (int s = 0; s < SLOTS; ++s) t += acc[s * 8 + jj];
        S[jj] = t;
    }
    __syncthreads();
    if (jj == 0) {
        const double bce   = S[0] / (double)N_TOT;
        const double dice  = (2.0 * S[3] + 1.0) / (S[1] + S[2] + 1.0);
        const double tprec = (S[5] + 1.0) / (S[4] + 1.0);
        const double tsens = (S[7] + 1.0) / (S[6] + 1.0);
        const double cl    = 2.0 * tprec * tsens / (tprec + tsens + 1e-7);
        out[0] = (float)(0.3 * bce + 0.3 * (1.0 - dice) + 0.4 * (1.0 - cl));
    }
}

// ---------------------------------------------------------------------------
extern "C" void kernel_launch(void* const* d_in, const int* in_sizes, int n_in,
                              void* d_out, int out_size, void* d_ws, size_t ws_size,
                              hipStream_t stream)
{
    const float* pred = (const float*)d_in[0];
    const float* tgt  = (const float*)d_in[1];
    float* out = (float*)d_out;
    double* acc = (double*)d_ws;                  // SLOTS*8 doubles = 2 KB

    zero_acc<<<1, SLOTS * 8, 0, stream>>>(acc);

    const dim3 grid(W_IMG / TILE, H_IMG / TILE, 2 * N_B);   // (16,16,32)
    skel_all<<<grid, 512, 0, stream>>>(pred, tgt, acc);

    finalize_k<<<1, 64, 0, stream>>>(acc, out);
}

// Round 4
// 601.942 us; speedup vs baseline: 1.3180x; 1.3180x over previous
//
#include <hip/hip_runtime.h>
#include <math.h>

// Geometry (fixed): B=16, C=1, H=W=1024, f32.
#define H_IMG 1024
#define W_IMG 1024
#define N_B   16
#define NPIX  (H_IMG * W_IMG)
#define N_TOT (16LL * NPIX)

// 64x64 owned tile, halo 12 (11 fused erode iters + 1 dilate ring).
#define TILE 64
#define HALO 12
#define RG   88          // TILE + 2*HALO rows / data cols
#define RST  92          // LDS row stride (floats) = 23 float4 strips (22 data + 1 pad)
#define SLOTS 32         // atomic accumulator slots (each its own 64B line)

__device__ __forceinline__ float sigm(float x)  { return 1.0f / (1.0f + __expf(-x)); }
__device__ __forceinline__ float min3f(float a, float b, float c) { return fminf(fminf(a, b), c); }
__device__ __forceinline__ float max3f(float a, float b, float c) { return fmaxf(fmaxf(a, b), c); }

// Overwrite region cells whose GLOBAL coords are outside the image with +INF
// (erode-input identity). Stride-1 b32 writes: conflict-free.
__device__ __forceinline__ void band_fix_inf(float* b, int r0, int c0, int tid)
{
    const float val = __builtin_inff();
    if (r0 == 0) {
        for (int idx = tid; idx < HALO * RG; idx += 512) {
            const int r = idx / RG, c = idx - r * RG;
            b[r * RST + c] = val;
        }
    }
    if (r0 == H_IMG - TILE) {
        for (int idx = tid; idx < HALO * RG; idx += 512) {
            const int r = idx / RG, c = idx - r * RG;
            b[(RG - HALO + r) * RST + c] = val;
        }
    }
    if (c0 == 0) {
        for (int idx = tid; idx < RG * HALO; idx += 512) {
            const int r = idx / HALO, c = idx - r * HALO;
            b[r * RST + c] = val;
        }
    }
    if (c0 == W_IMG - TILE) {
        for (int idx = tid; idx < RG * HALO; idx += 512) {
            const int r = idx / HALO, c = idx - r * HALO;
            b[r * RST + (RG - HALO + c)] = val;
        }
    }
}

// ---------------------------------------------------------------------------
// Whole soft_skeleton (11 iters) for one 64x64 tile in LDS, plus fused
// reductions. Bank-conflict design (8-lane-issue-group model):
//  * every b128 access: 8 consecutive lanes = 1 row x 8 consecutive strips ->
//    start banks {C,C+4,...,C+28} = exact 32-bank cover, conflict-free.
//  * horizontal +/-1 neighbors (addr === const mod 4 -> 8-bank class, was
//    8-way conflicted as wave-wide b32) now come from adjacent-lane registers
//    via __shfl (ds_bpermute, conflict-free); boundary lanes fall back to
//    masked LDS reads on DISTINCT rows -> distinct banks.
//  * dilate is separable: V = max3 vertical (aligned b128 only), then
//    horizontal max3 of V with seam values shuffled across lanes.
// ---------------------------------------------------------------------------
template<bool SIG_SRC, bool SIG_OTH, bool DO_BCE, int CBASE>
__device__ __forceinline__
void skel_core(const float* __restrict__ src, const float* __restrict__ oth,
               double* __restrict__ acc, float* cur, float* nxt, float* red,
               int z, int r0, int c0, int tid, int bid)
{
    const float* s = src + (size_t)z * NPIX;

    // ---- load 88x88 region (+4-col pad), phase-aligned ----
    {   // phase A: strips 0..15, 1 row x 16 strips per quarter-wave
        const int st = tid & 15, c = 4 * st;
        const int gc = c0 - HALO + c;
        const bool vec = (gc >= 0) && (gc + 3 < W_IMG);
        for (int r = tid >> 4; r < RG; r += 32) {
            const int gr = min(max(r0 - HALO + r, 0), H_IMG - 1);
            const float* row = s + (size_t)gr * W_IMG;
            float4 v;
            if (vec) v = *(const float4*)&row[gc];
            else {
                v.x = row[min(max(gc + 0, 0), W_IMG - 1)];
                v.y = row[min(max(gc + 1, 0), W_IMG - 1)];
                v.z = row[min(max(gc + 2, 0), W_IMG - 1)];
                v.w = row[min(max(gc + 3, 0), W_IMG - 1)];
            }
            if (SIG_SRC) { v.x = sigm(v.x); v.y = sigm(v.y); v.z = sigm(v.z); v.w = sigm(v.w); }
            *(float4*)&cur[r * RST + c] = v;
        }
    }
    {   // phase B: strips 16..22 (incl pad strip 22), 2 rows x 8 strips
        const int st = 16 + (tid & 7);
        if (st < 23) {
            const int c = 4 * st, gc = c0 - HALO + c;
            const bool vec = (gc >= 0) && (gc + 3 < W_IMG);
            for (int r = tid >> 3; r < RG; r += 64) {
                const int gr = min(max(r0 - HALO + r, 0), H_IMG - 1);
                const float* row = s + (size_t)gr * W_IMG;
                float4 v;
                if (vec) v = *(const float4*)&row[gc];
                else {
                    v.x = row[min(max(gc + 0, 0), W_IMG - 1)];
                    v.y = row[min(max(gc + 1, 0), W_IMG - 1)];
                    v.z = row[min(max(gc + 2, 0), W_IMG - 1)];
                    v.w = row[min(max(gc + 3, 0), W_IMG - 1)];
                }
                if (SIG_SRC) { v.x = sigm(v.x); v.y = sigm(v.y); v.z = sigm(v.z); v.w = sigm(v.w); }
                *(float4*)&cur[r * RST + c] = v;
            }
        }
    }
    __syncthreads();

    const bool edge = (r0 == 0) | (c0 == 0) | (r0 == H_IMG - TILE) | (c0 == W_IMG - TILE);
    const float NINF = -__builtin_inff();

    float4 sk[2];
    sk[0] = make_float4(0.f, 0.f, 0.f, 0.f);
    sk[1] = make_float4(0.f, 0.f, 0.f, 0.f);

    const int oy = tid >> 3;      // owned row 0..63
    const int j  = tid & 7;       // strip slot (strips j, j+8 of owned)
    const int rr = HALO + oy;

    for (int k = 0; k < 11; ++k) {
        if (edge) { band_fix_inf(cur, r0, c0, tid); __syncthreads(); }

        const int rlo = k + 1, rhi = RG - 1 - k;        // rows [rlo, rhi)
        const int sA = rlo >> 2, sE = (rhi + 3) >> 2;   // strips [sA, sE)

        // ---- erode phase A: strips sA..sA+15 (1 row x 16 strips/quarter) ----
        {
            const int l  = tid & 15;
            const int st = sA + l;
            const int c  = 4 * st;
            const int gcb = c0 - HALO + c;
            const bool cOOB = ((unsigned)gcb > (unsigned)(W_IMG - 4));
            for (int r = rlo + (tid >> 4); r < rhi; r += 32) {
                const int base = r * RST + c;
                const float4 mid = *(const float4*)&cur[base];
                const float4 up  = *(const float4*)&cur[base - RST];
                const float4 dn  = *(const float4*)&cur[base + RST];
                float lfv = __shfl_up(mid.w, 1);      // strip st-1 .w (same row for l>0)
                float rtv = __shfl_down(mid.x, 1);    // strip st+1 .x (same row for l<15)
                if (l == 0)  lfv = cur[base - 1];
                if (l == 15) rtv = cur[base + 4];
                float4 e;
                e.x = fminf(min3f(up.x, mid.x, dn.x), fminf(lfv,   mid.y));
                e.y = fminf(min3f(up.y, mid.y, dn.y), fminf(mid.x, mid.z));
                e.z = fminf(min3f(up.z, mid.z, dn.z), fminf(mid.y, mid.w));
                e.w = fminf(min3f(up.w, mid.w, dn.w), fminf(mid.z, rtv));
                if (edge) {
                    const int gr = r0 - HALO + r;
                    if (((unsigned)gr >= (unsigned)H_IMG) | cOOB) { e.x = e.y = e.z = e.w = NINF; }
                }
                *(float4*)&nxt[base] = e;
            }
        }
        // ---- erode phase B: strips sA+16..sE-1 (2 rows x 8 strips/quarter) ----
        {
            const int l  = tid & 7;
            const int st = sA + 16 + l;
            if (st < sE) {
                const int c = 4 * st;
                const int gcb = c0 - HALO + c;
                const bool cOOB  = ((unsigned)gcb > (unsigned)(W_IMG - 4));
                const bool lastS = (st == sE - 1);
                for (int r = rlo + (tid >> 3); r < rhi; r += 64) {
                    const int base = r * RST + c;
                    const float4 mid = *(const float4*)&cur[base];
                    const float4 up  = *(const float4*)&cur[base - RST];
                    const float4 dn  = *(const float4*)&cur[base + RST];
                    float lfv = __shfl_up(mid.w, 1);
                    float rtv = __shfl_down(mid.x, 1);
                    if (l == 0)  lfv = cur[base - 1];
                    if (lastS)   rtv = cur[base + 4];
                    float4 e;
                    e.x = fminf(min3f(up.x, mid.x, dn.x), fminf(lfv,   mid.y));
                    e.y = fminf(min3f(up.y, mid.y, dn.y), fminf(mid.x, mid.z));
                    e.z = fminf(min3f(up.z, mid.z, dn.z), fminf(mid.y, mid.w));
                    e.w = fminf(min3f(up.w, mid.w, dn.w), fminf(mid.z, rtv));
                    if (edge) {
                        const int gr = r0 - HALO + r;
                        if (((unsigned)gr >= (unsigned)H_IMG) | cOOB) { e.x = e.y = e.z = e.w = NINF; }
                    }
                    *(float4*)&nxt[base] = e;
                }
            }
        }
        __syncthreads();

        // ---- dilate(ernew) at owned pixels + skel update (separable V/H) ----
        {
            const int cA = HALO + 4 * j;           // strip j
            const int cB = cA + 32;                // strip j+8
            const int bA = rr * RST + cA;
            const int bB = rr * RST + cB;
            const float4 a0 = *(const float4*)&nxt[bA - RST];
            const float4 m0 = *(const float4*)&nxt[bA];
            const float4 d0 = *(const float4*)&nxt[bA + RST];
            const float4 a1 = *(const float4*)&nxt[bB - RST];
            const float4 m1 = *(const float4*)&nxt[bB];
            const float4 d1 = *(const float4*)&nxt[bB + RST];
            float4 V0, V1;   // vertical max3 per strip
            V0.x = max3f(a0.x, m0.x, d0.x); V0.y = max3f(a0.y, m0.y, d0.y);
            V0.z = max3f(a0.z, m0.z, d0.z); V0.w = max3f(a0.w, m0.w, d0.w);
            V1.x = max3f(a1.x, m1.x, d1.x); V1.y = max3f(a1.y, m1.y, d1.y);
            V1.z = max3f(a1.z, m1.z, d1.z); V1.w = max3f(a1.w, m1.w, d1.w);
            // horizontal neighbors of V via register shuffles (same row octet)
            const float sh_vl0  = __shfl_up  (V0.w, 1);   // strip j-1  .w
            const float sh_vr0a = __shfl_down(V0.x, 1);   // strip j+1  .x
            const float sh_vr0b = __shfl_up  (V1.x, 7);   // strip 8    .x  (j==7 seam)
            const float sh_vl1a = __shfl_up  (V1.w, 1);   // strip j+7  .w
            const float sh_vl1b = __shfl_down(V0.w, 7);   // strip 7    .w  (j==0 seam)
            const float sh_vr1  = __shfl_down(V1.x, 1);   // strip j+9  .x
            float vl0 = sh_vl0;
            float vr0 = (j == 7) ? sh_vr0b : sh_vr0a;
            float vl1 = (j == 0) ? sh_vl1b : sh_vl1a;
            float vr1 = sh_vr1;
            if (j == 0)   // block-left halo col 11 (8 lanes/wave, distinct rows->banks)
                vl0 = max3f(nxt[bA - RST - 1], nxt[bA - 1], nxt[bA + RST - 1]);
            if (j == 7)   // block-right halo col 76
                vr1 = max3f(nxt[bB - RST + 4], nxt[bB + 4], nxt[bB + RST + 4]);
            const float4 e0 = *(const float4*)&cur[bA];   // er_k at owned
            const float4 e1 = *(const float4*)&cur[bB];
            float o, dd;
            o = max3f(vl0,  V0.x, V0.y); dd = fmaxf(e0.x - o, 0.f); sk[0].x += fmaxf(dd - sk[0].x * dd, 0.f);
            o = max3f(V0.x, V0.y, V0.z); dd = fmaxf(e0.y - o, 0.f); sk[0].y += fmaxf(dd - sk[0].y * dd, 0.f);
            o = max3f(V0.y, V0.z, V0.w); dd = fmaxf(e0.z - o, 0.f); sk[0].z += fmaxf(dd - sk[0].z * dd, 0.f);
            o = max3f(V0.z, V0.w, vr0 ); dd = fmaxf(e0.w - o, 0.f); sk[0].w += fmaxf(dd - sk[0].w * dd, 0.f);
            o = max3f(vl1,  V1.x, V1.y); dd = fmaxf(e1.x - o, 0.f); sk[1].x += fmaxf(dd - sk[1].x * dd, 0.f);
            o = max3f(V1.x, V1.y, V1.z); dd = fmaxf(e1.y - o, 0.f); sk[1].y += fmaxf(dd - sk[1].y * dd, 0.f);
            o = max3f(V1.y, V1.z, V1.w); dd = fmaxf(e1.z - o, 0.f); sk[1].z += fmaxf(dd - sk[1].z * dd, 0.f);
            o = max3f(V1.z, V1.w, vr1 ); dd = fmaxf(e1.w - o, 0.f); sk[1].w += fmaxf(dd - sk[1].w * dd, 0.f);
        }
        __syncthreads();

        float* tp = cur; cur = nxt; nxt = tp;
    }

    // ---- fused reductions over owned pixels ----
    const size_t gbase = (size_t)z * NPIX + (size_t)(r0 + oy) * W_IMG + c0;
    const float* op = oth + gbase;
    const float* pp = src + gbase;   // pred logits (DO_BCE only)
    float ss = 0.f, sso = 0.f, sb = 0.f, sp = 0.f, sy = 0.f, spy = 0.f;
    #pragma unroll
    for (int t = 0; t < 2; ++t) {
        const int cc = 4 * (j + 8 * t);
        float4 ov = *(const float4*)&op[cc];
        float o0 = ov.x, o1 = ov.y, o2 = ov.z, o3 = ov.w;
        if (SIG_OTH) { o0 = sigm(o0); o1 = sigm(o1); o2 = sigm(o2); o3 = sigm(o3); }
        ss  += sk[t].x + sk[t].y + sk[t].z + sk[t].w;
        sso += sk[t].x * o0 + sk[t].y * o1 + sk[t].z * o2 + sk[t].w * o3;
        if (DO_BCE) {
            const float4 xv = *(const float4*)&pp[cc];
            const float xs[4] = {xv.x, xv.y, xv.z, xv.w};
            const float ys[4] = {o0, o1, o2, o3};   // SIG_OTH=false here: raw target
            #pragma unroll
            for (int q = 0; q < 4; ++q) {
                const float x = xs[q], y = ys[q];
                const float zz = __expf(-fabsf(x));
                const float inv = 1.0f / (1.0f + zz);
                sb += fmaxf(x, 0.f) + __logf(1.0f + zz) - y * x;
                const float p = (x >= 0.f) ? inv : zz * inv;
                sp += p; sy += y; spy += p * y;
            }
        }
    }
    for (int off = 32; off > 0; off >>= 1) {
        ss  += __shfl_down(ss,  off);
        sso += __shfl_down(sso, off);
        if (DO_BCE) {
            sb  += __shfl_down(sb,  off);
            sp  += __shfl_down(sp,  off);
            sy  += __shfl_down(sy,  off);
            spy += __shfl_down(spy, off);
        }
    }
    const int wid = tid >> 6, lane = tid & 63;
    if (lane == 0) {
        red[0 * 8 + wid] = ss;  red[1 * 8 + wid] = sso;
        if (DO_BCE) {
            red[2 * 8 + wid] = sb;  red[3 * 8 + wid] = sp;
            red[4 * 8 + wid] = sy;  red[5 * 8 + wid] = spy;
        }
    }
    __syncthreads();
    if (tid == 0) {
        double SS = 0, SO = 0, B0 = 0, B1 = 0, B2 = 0, B3 = 0;
        for (int w = 0; w < 8; ++w) {
            SS += (double)red[0 * 8 + w];  SO += (double)red[1 * 8 + w];
            if (DO_BCE) {
                B0 += (double)red[2 * 8 + w]; B1 += (double)red[3 * 8 + w];
                B2 += (double)red[4 * 8 + w]; B3 += (double)red[5 * 8 + w];
            }
        }
        const int slot = bid & (SLOTS - 1);
        atomicAdd(&acc[slot * 8 + CBASE],     SS);
        atomicAdd(&acc[slot * 8 + CBASE + 1], SO);
        if (DO_BCE) {
            atomicAdd(&acc[slot * 8 + 0], B0);
            atomicAdd(&acc[slot * 8 + 1], B1);
            atomicAdd(&acc[slot * 8 + 2], B2);
            atomicAdd(&acc[slot * 8 + 3], B3);
        }
    }
}

// Both skeletons in one dispatch: z<16 -> skel(sigmoid(pred)) + BCE/dice sums;
// z>=16 -> skel(target), reduced against sigmoid(pred).
__global__ __launch_bounds__(512, 4)
void skel_all(const float* __restrict__ pred, const float* __restrict__ tgt,
              double* __restrict__ acc)
{
    __shared__ __align__(16) float buf0[RG * RST];
    __shared__ __align__(16) float buf1[RG * RST];
    __shared__ float red[48];
    const int tid = threadIdx.x;
    const int r0 = blockIdx.y * TILE, c0 = blockIdx.x * TILE;
    const int bid = ((int)blockIdx.z & 15) * 256 + blockIdx.y * 16 + blockIdx.x;
    if ((int)blockIdx.z < N_B)
        skel_core<true,  false, true,  4>(pred, tgt, acc, buf0, buf1, red,
                                          blockIdx.z, r0, c0, tid, bid);
    else
        skel_core<false, true,  false, 6>(tgt, pred, acc, buf0, buf1, red,
                                          blockIdx.z - N_B, r0, c0, tid, bid);
}

__global__ void zero_acc(double* acc) { acc[threadIdx.x] = 0.0; }

__global__ void finalize_k(const double* __restrict__ acc, float* __restrict__ out)
{
    __shared__ double S[8];
    const int jj = threadIdx.x;
    if (jj < 8) {
        double t = 0.0;
        for (int s = 0; s < SLOTS; ++s) t += acc[s * 8 + jj];
        S[jj] = t;
    }
    __syncthreads();
    if (jj == 0) {
        const double bce   = S[0] / (double)N_TOT;
        const double dice  = (2.0 * S[3] + 1.0) / (S[1] + S[2] + 1.0);
        const double tprec = (S[5] + 1.0) / (S[4] + 1.0);
        const double tsens = (S[7] + 1.0) / (S[6] + 1.0);
        const double cl    = 2.0 * tprec * tsens / (tprec + tsens + 1e-7);
        out[0] = (float)(0.3 * bce + 0.3 * (1.0 - dice) + 0.4 * (1.0 - cl));
    }
}

// ---------------------------------------------------------------------------
extern "C" void kernel_launch(void* const* d_in, const int* in_sizes, int n_in,
                              void* d_out, int out_size, void* d_ws, size_t ws_size,
                              hipStream_t stream)
{
    const float* pred = (const float*)d_in[0];
    const float* tgt  = (const float*)d_in[1];
    float* out = (float*)d_out;
    double* acc = (double*)d_ws;                  // SLOTS*8 doubles = 2 KB

    zero_acc<<<1, SLOTS * 8, 0, stream>>>(acc);

    const dim3 grid(W_IMG / TILE, H_IMG / TILE, 2 * N_B);   // (16,16,32)
    skel_all<<<grid, 512, 0, stream>>>(pred, tgt, acc);

    finalize_k<<<1, 64, 0, stream>>>(acc, out);
}

// Round 5
// 460.474 us; speedup vs baseline: 1.7230x; 1.3072x over previous
//
#include <hip/hip_runtime.h>
#include <hip/hip_fp16.h>
#include <math.h>

// Geometry (fixed): B=16, C=1, H=W=1024, f32.
#define H_IMG 1024
#define W_IMG 1024
#define N_B   16
#define NPIX  (H_IMG * W_IMG)
#define N_TOT (16LL * NPIX)

// 64x64 owned tile, halo 12 (11 fused erode iters + 1 dilate ring).
// LDS tiles stored as fp16: values are [0,1] probabilities (or +/-inf bands);
// min/max of f16 values is f16-exact, so only the initial store rounds (2^-11).
#define TILE 64
#define HALO 12
#define RG   88          // TILE + 2*HALO rows / data cols
#define HST  92          // LDS row stride in halfs (184 B -> bank step 14, clean)
#define SLOTS 32         // atomic accumulator slots (each its own 64B line)

__device__ __forceinline__ float sigm(float x)  { return 1.0f / (1.0f + __expf(-x)); }
__device__ __forceinline__ float min3f(float a, float b, float c) { return fminf(fminf(a, b), c); }
__device__ __forceinline__ float max3f(float a, float b, float c) { return fmaxf(fmaxf(a, b), c); }

union H2U { __half2 h; unsigned u; };

// 4-px strip load/store, guaranteed single ds_read_b64 / ds_write_b64.
__device__ __forceinline__ float4 ld4h(const __half* p) {
    const uint2 u = *(const uint2*)p;
    H2U a, b; a.u = u.x; b.u = u.y;
    const float2 fa = __half22float2(a.h);
    const float2 fb = __half22float2(b.h);
    return make_float4(fa.x, fa.y, fb.x, fb.y);
}
__device__ __forceinline__ void st4h(__half* p, float x, float y, float z, float w) {
    H2U a, b;
    a.h = __floats2half2_rn(x, y);
    b.h = __floats2half2_rn(z, w);
    *(uint2*)p = make_uint2(a.u, b.u);
}
__device__ __forceinline__ float ldh(const __half* p) { return __half2float(*p); }

// Overwrite region cells whose GLOBAL coords are outside the image with +INF
// (erode-input identity). b16 stores, consecutive addresses: conflict-free.
__device__ __forceinline__ void band_fix_inf(__half* b, int r0, int c0, int tid)
{
    unsigned short* u = (unsigned short*)b;
    const unsigned short val = 0x7C00;   // +inf f16
    if (r0 == 0) {
        for (int idx = tid; idx < HALO * RG; idx += 512) {
            const int r = idx / RG, c = idx - r * RG;
            u[r * HST + c] = val;
        }
    }
    if (r0 == H_IMG - TILE) {
        for (int idx = tid; idx < HALO * RG; idx += 512) {
            const int r = idx / RG, c = idx - r * RG;
            u[(RG - HALO + r) * HST + c] = val;
        }
    }
    if (c0 == 0) {
        for (int idx = tid; idx < RG * HALO; idx += 512) {
            const int r = idx / HALO, c = idx - r * HALO;
            u[r * HST + c] = val;
        }
    }
    if (c0 == W_IMG - TILE) {
        for (int idx = tid; idx < RG * HALO; idx += 512) {
            const int r = idx / HALO, c = idx - r * HALO;
            u[r * HST + (RG - HALO + c)] = val;
        }
    }
}

// ---------------------------------------------------------------------------
// Whole soft_skeleton (11 iters) for one 64x64 tile in fp16 LDS, plus fused
// reductions. Bank-conflict design (8-lane-issue-group model):
//  * b64 strip ops: 8 consecutive lanes = 1 row x 8 consecutive strips ->
//    16 banks x 2-way = free (m136).
//  * horizontal +/-1 neighbors via adjacent-lane __shfl; boundary lanes fall
//    back to scalar u16 LDS reads on distinct rows -> distinct banks.
//  * dilate separable: V = vertical max3 (aligned b64 only), horizontal max3
//    of V via register shuffles.
// ---------------------------------------------------------------------------
template<bool SIG_SRC, bool SIG_OTH, bool DO_BCE, int CBASE>
__device__ __forceinline__
void skel_core(const float* __restrict__ src, const float* __restrict__ oth,
               double* __restrict__ acc, __half* cur, __half* nxt, float* red,
               int z, int r0, int c0, int tid, int bid)
{
    const float* s = src + (size_t)z * NPIX;

    // ---- load 88x88 region (+4-col pad), phase-aligned ----
    {   // phase A: strips 0..15, 1 row x 16 strips per quarter-wave
        const int st = tid & 15, c = 4 * st;
        const int gc = c0 - HALO + c;
        const bool vec = (gc >= 0) && (gc + 3 < W_IMG);
        for (int r = tid >> 4; r < RG; r += 32) {
            const int gr = min(max(r0 - HALO + r, 0), H_IMG - 1);
            const float* row = s + (size_t)gr * W_IMG;
            float4 v;
            if (vec) v = *(const float4*)&row[gc];
            else {
                v.x = row[min(max(gc + 0, 0), W_IMG - 1)];
                v.y = row[min(max(gc + 1, 0), W_IMG - 1)];
                v.z = row[min(max(gc + 2, 0), W_IMG - 1)];
                v.w = row[min(max(gc + 3, 0), W_IMG - 1)];
            }
            if (SIG_SRC) { v.x = sigm(v.x); v.y = sigm(v.y); v.z = sigm(v.z); v.w = sigm(v.w); }
            st4h(&cur[r * HST + c], v.x, v.y, v.z, v.w);
        }
    }
    {   // phase B: strips 16..22 (incl pad strip 22), 2 rows x 8 strips
        const int st = 16 + (tid & 7);
        if (st < 23) {
            const int c = 4 * st, gc = c0 - HALO + c;
            const bool vec = (gc >= 0) && (gc + 3 < W_IMG);
            for (int r = tid >> 3; r < RG; r += 64) {
                const int gr = min(max(r0 - HALO + r, 0), H_IMG - 1);
                const float* row = s + (size_t)gr * W_IMG;
                float4 v;
                if (vec) v = *(const float4*)&row[gc];
                else {
                    v.x = row[min(max(gc + 0, 0), W_IMG - 1)];
                    v.y = row[min(max(gc + 1, 0), W_IMG - 1)];
                    v.z = row[min(max(gc + 2, 0), W_IMG - 1)];
                    v.w = row[min(max(gc + 3, 0), W_IMG - 1)];
                }
                if (SIG_SRC) { v.x = sigm(v.x); v.y = sigm(v.y); v.z = sigm(v.z); v.w = sigm(v.w); }
                st4h(&cur[r * HST + c], v.x, v.y, v.z, v.w);
            }
        }
    }
    __syncthreads();

    const bool edge = (r0 == 0) | (c0 == 0) | (r0 == H_IMG - TILE) | (c0 == W_IMG - TILE);
    const float NINF = -__builtin_inff();

    float4 sk[2];
    sk[0] = make_float4(0.f, 0.f, 0.f, 0.f);
    sk[1] = make_float4(0.f, 0.f, 0.f, 0.f);

    const int oy = tid >> 3;      // owned row 0..63
    const int j  = tid & 7;       // strip slot (strips j, j+8 of owned)
    const int rr = HALO + oy;

    for (int k = 0; k < 11; ++k) {
        if (edge) { band_fix_inf(cur, r0, c0, tid); __syncthreads(); }

        const int rlo = k + 1, rhi = RG - 1 - k;        // rows [rlo, rhi)
        const int sA = rlo >> 2, sE = (rhi + 3) >> 2;   // strips [sA, sE)

        // ---- erode phase A: strips sA..sA+15 (1 row x 16 strips/quarter) ----
        {
            const int l  = tid & 15;
            const int st = sA + l;
            const int c  = 4 * st;
            const int gcb = c0 - HALO + c;
            const bool cOOB = ((unsigned)gcb > (unsigned)(W_IMG - 4));
            for (int r = rlo + (tid >> 4); r < rhi; r += 32) {
                const int base = r * HST + c;
                const float4 mid = ld4h(&cur[base]);
                const float4 up  = ld4h(&cur[base - HST]);
                const float4 dn  = ld4h(&cur[base + HST]);
                float lfv = __shfl_up(mid.w, 1);      // strip st-1 .w (same row for l>0)
                float rtv = __shfl_down(mid.x, 1);    // strip st+1 .x (same row for l<15)
                if (l == 0)  lfv = ldh(&cur[base - 1]);
                if (l == 15) rtv = ldh(&cur[base + 4]);
                float ex = fminf(min3f(up.x, mid.x, dn.x), fminf(lfv,   mid.y));
                float ey = fminf(min3f(up.y, mid.y, dn.y), fminf(mid.x, mid.z));
                float ez = fminf(min3f(up.z, mid.z, dn.z), fminf(mid.y, mid.w));
                float ew = fminf(min3f(up.w, mid.w, dn.w), fminf(mid.z, rtv));
                if (edge) {
                    const int gr = r0 - HALO + r;
                    if (((unsigned)gr >= (unsigned)H_IMG) | cOOB) { ex = ey = ez = ew = NINF; }
                }
                st4h(&nxt[base], ex, ey, ez, ew);
            }
        }
        // ---- erode phase B: strips sA+16..sE-1 (2 rows x 8 strips/quarter) ----
        {
            const int l  = tid & 7;
            const int st = sA + 16 + l;
            if (st < sE) {
                const int c = 4 * st;
                const int gcb = c0 - HALO + c;
                const bool cOOB  = ((unsigned)gcb > (unsigned)(W_IMG - 4));
                const bool lastS = (st == sE - 1);
                for (int r = rlo + (tid >> 3); r < rhi; r += 64) {
                    const int base = r * HST + c;
                    const float4 mid = ld4h(&cur[base]);
                    const float4 up  = ld4h(&cur[base - HST]);
                    const float4 dn  = ld4h(&cur[base + HST]);
                    float lfv = __shfl_up(mid.w, 1);
                    float rtv = __shfl_down(mid.x, 1);
                    if (l == 0)  lfv = ldh(&cur[base - 1]);
                    if (lastS)   rtv = ldh(&cur[base + 4]);
                    float ex = fminf(min3f(up.x, mid.x, dn.x), fminf(lfv,   mid.y));
                    float ey = fminf(min3f(up.y, mid.y, dn.y), fminf(mid.x, mid.z));
                    float ez = fminf(min3f(up.z, mid.z, dn.z), fminf(mid.y, mid.w));
                    float ew = fminf(min3f(up.w, mid.w, dn.w), fminf(mid.z, rtv));
                    if (edge) {
                        const int gr = r0 - HALO + r;
                        if (((unsigned)gr >= (unsigned)H_IMG) | cOOB) { ex = ey = ez = ew = NINF; }
                    }
                    st4h(&nxt[base], ex, ey, ez, ew);
                }
            }
        }
        __syncthreads();

        // ---- dilate(ernew) at owned pixels + skel update (separable V/H) ----
        {
            const int cA = HALO + 4 * j;           // strip j
            const int cB = cA + 32;                // strip j+8
            const int bA = rr * HST + cA;
            const int bB = rr * HST + cB;
            const float4 a0 = ld4h(&nxt[bA - HST]);
            const float4 m0 = ld4h(&nxt[bA]);
            const float4 d0 = ld4h(&nxt[bA + HST]);
            const float4 a1 = ld4h(&nxt[bB - HST]);
            const float4 m1 = ld4h(&nxt[bB]);
            const float4 d1 = ld4h(&nxt[bB + HST]);
            float4 V0, V1;   // vertical max3 per strip
            V0.x = max3f(a0.x, m0.x, d0.x); V0.y = max3f(a0.y, m0.y, d0.y);
            V0.z = max3f(a0.z, m0.z, d0.z); V0.w = max3f(a0.w, m0.w, d0.w);
            V1.x = max3f(a1.x, m1.x, d1.x); V1.y = max3f(a1.y, m1.y, d1.y);
            V1.z = max3f(a1.z, m1.z, d1.z); V1.w = max3f(a1.w, m1.w, d1.w);
            // horizontal neighbors of V via register shuffles (same row octet)
            const float sh_vl0  = __shfl_up  (V0.w, 1);   // strip j-1  .w
            const float sh_vr0a = __shfl_down(V0.x, 1);   // strip j+1  .x
            const float sh_vr0b = __shfl_up  (V1.x, 7);   // strip 8    .x  (j==7 seam)
            const float sh_vl1a = __shfl_up  (V1.w, 1);   // strip j+7  .w
            const float sh_vl1b = __shfl_down(V0.w, 7);   // strip 7    .w  (j==0 seam)
            const float sh_vr1  = __shfl_down(V1.x, 1);   // strip j+9  .x
            float vl0 = sh_vl0;
            float vr0 = (j == 7) ? sh_vr0b : sh_vr0a;
            float vl1 = (j == 0) ? sh_vl1b : sh_vl1a;
            float vr1 = sh_vr1;
            if (j == 0)   // block-left halo col 11 (8 lanes/wave, distinct rows->banks)
                vl0 = max3f(ldh(&nxt[bA - HST - 1]), ldh(&nxt[bA - 1]), ldh(&nxt[bA + HST - 1]));
            if (j == 7)   // block-right halo col 76
                vr1 = max3f(ldh(&nxt[bB - HST + 4]), ldh(&nxt[bB + 4]), ldh(&nxt[bB + HST + 4]));
            const float4 e0 = ld4h(&cur[bA]);   // er_k at owned
            const float4 e1 = ld4h(&cur[bB]);
            float o, dd;
            o = max3f(vl0,  V0.x, V0.y); dd = fmaxf(e0.x - o, 0.f); sk[0].x += fmaxf(dd - sk[0].x * dd, 0.f);
            o = max3f(V0.x, V0.y, V0.z); dd = fmaxf(e0.y - o, 0.f); sk[0].y += fmaxf(dd - sk[0].y * dd, 0.f);
            o = max3f(V0.y, V0.z, V0.w); dd = fmaxf(e0.z - o, 0.f); sk[0].z += fmaxf(dd - sk[0].z * dd, 0.f);
            o = max3f(V0.z, V0.w, vr0 ); dd = fmaxf(e0.w - o, 0.f); sk[0].w += fmaxf(dd - sk[0].w * dd, 0.f);
            o = max3f(vl1,  V1.x, V1.y); dd = fmaxf(e1.x - o, 0.f); sk[1].x += fmaxf(dd - sk[1].x * dd, 0.f);
            o = max3f(V1.x, V1.y, V1.z); dd = fmaxf(e1.y - o, 0.f); sk[1].y += fmaxf(dd - sk[1].y * dd, 0.f);
            o = max3f(V1.y, V1.z, V1.w); dd = fmaxf(e1.z - o, 0.f); sk[1].z += fmaxf(dd - sk[1].z * dd, 0.f);
            o = max3f(V1.z, V1.w, vr1 ); dd = fmaxf(e1.w - o, 0.f); sk[1].w += fmaxf(dd - sk[1].w * dd, 0.f);
        }
        __syncthreads();

        __half* tp = cur; cur = nxt; nxt = tp;
    }

    // ---- fused reductions over owned pixels ----
    const size_t gbase = (size_t)z * NPIX + (size_t)(r0 + oy) * W_IMG + c0;
    const float* op = oth + gbase;
    const float* pp = src + gbase;   // pred logits (DO_BCE only)
    float ss = 0.f, sso = 0.f, sb = 0.f, sp = 0.f, sy = 0.f, spy = 0.f;
    #pragma unroll
    for (int t = 0; t < 2; ++t) {
        const int cc = 4 * (j + 8 * t);
        float4 ov = *(const float4*)&op[cc];
        float o0 = ov.x, o1 = ov.y, o2 = ov.z, o3 = ov.w;
        if (SIG_OTH) { o0 = sigm(o0); o1 = sigm(o1); o2 = sigm(o2); o3 = sigm(o3); }
        ss  += sk[t].x + sk[t].y + sk[t].z + sk[t].w;
        sso += sk[t].x * o0 + sk[t].y * o1 + sk[t].z * o2 + sk[t].w * o3;
        if (DO_BCE) {
            const float4 xv = *(const float4*)&pp[cc];
            const float xs[4] = {xv.x, xv.y, xv.z, xv.w};
            const float ys[4] = {o0, o1, o2, o3};   // SIG_OTH=false here: raw target
            #pragma unroll
            for (int q = 0; q < 4; ++q) {
                const float x = xs[q], y = ys[q];
                const float zz = __expf(-fabsf(x));
                const float inv = 1.0f / (1.0f + zz);
                sb += fmaxf(x, 0.f) + __logf(1.0f + zz) - y * x;
                const float p = (x >= 0.f) ? inv : zz * inv;
                sp += p; sy += y; spy += p * y;
            }
        }
    }
    for (int off = 32; off > 0; off >>= 1) {
        ss  += __shfl_down(ss,  off);
        sso += __shfl_down(sso, off);
        if (DO_BCE) {
            sb  += __shfl_down(sb,  off);
            sp  += __shfl_down(sp,  off);
            sy  += __shfl_down(sy,  off);
            spy += __shfl_down(spy, off);
        }
    }
    const int wid = tid >> 6, lane = tid & 63;
    if (lane == 0) {
        red[0 * 8 + wid] = ss;  red[1 * 8 + wid] = sso;
        if (DO_BCE) {
            red[2 * 8 + wid] = sb;  red[3 * 8 + wid] = sp;
            red[4 * 8 + wid] = sy;  red[5 * 8 + wid] = spy;
        }
    }
    __syncthreads();
    if (tid == 0) {
        double SS = 0, SO = 0, B0 = 0, B1 = 0, B2 = 0, B3 = 0;
        for (int w = 0; w < 8; ++w) {
            SS += (double)red[0 * 8 + w];  SO += (double)red[1 * 8 + w];
            if (DO_BCE) {
                B0 += (double)red[2 * 8 + w]; B1 += (double)red[3 * 8 + w];
                B2 += (double)red[4 * 8 + w]; B3 += (double)red[5 * 8 + w];
            }
        }
        const int slot = bid & (SLOTS - 1);
        atomicAdd(&acc[slot * 8 + CBASE],     SS);
        atomicAdd(&acc[slot * 8 + CBASE + 1], SO);
        if (DO_BCE) {
            atomicAdd(&acc[slot * 8 + 0], B0);
            atomicAdd(&acc[slot * 8 + 1], B1);
            atomicAdd(&acc[slot * 8 + 2], B2);
            atomicAdd(&acc[slot * 8 + 3], B3);
        }
    }
}

// Both skeletons in one dispatch: z<16 -> skel(sigmoid(pred)) + BCE/dice sums;
// z>=16 -> skel(target), reduced against sigmoid(pred).
__global__ __launch_bounds__(512, 8)
void skel_all(const float* __restrict__ pred, const float* __restrict__ tgt,
              double* __restrict__ acc)
{
    __shared__ __align__(16) __half buf0[RG * HST];
    __shared__ __align__(16) __half buf1[RG * HST];
    __shared__ float red[48];
    const int tid = threadIdx.x;
    const int r0 = blockIdx.y * TILE, c0 = blockIdx.x * TILE;
    const int bid = ((int)blockIdx.z & 15) * 256 + blockIdx.y * 16 + blockIdx.x;
    if ((int)blockIdx.z < N_B)
        skel_core<true,  false, true,  4>(pred, tgt, acc, buf0, buf1, red,
                                          blockIdx.z, r0, c0, tid, bid);
    else
        skel_core<false, true,  false, 6>(tgt, pred, acc, buf0, buf1, red,
                                          blockIdx.z - N_B, r0, c0, tid, bid);
}

__global__ void zero_acc(double* acc) { acc[threadIdx.x] = 0.0; }

__global__ void finalize_k(const double* __restrict__ acc, float* __restrict__ out)
{
    __shared__ double S[8];
    const int jj = threadIdx.x;
    if (jj < 8) {
        double t = 0.0;
        for (int s = 0; s < SLOTS; ++s) t += acc[s * 8 + jj];
        S[jj] = t;
    }
    __syncthreads();
    if (jj == 0) {
        const double bce   = S[0] / (double)N_TOT;
        const double dice  = (2.0 * S[3] + 1.0) / (S[1] + S[2] + 1.0);
        const double tprec = (S[5] + 1.0) / (S[4] + 1.0);
        const double tsens = (S[7] + 1.0) / (S[6] + 1.0);
        const double cl    = 2.0 * tprec * tsens / (tprec + tsens + 1e-7);
        out[0] = (float)(0.3 * bce + 0.3 * (1.0 - dice) + 0.4 * (1.0 - cl));
    }
}

// ---------------------------------------------------------------------------
extern "C" void kernel_launch(void* const* d_in, const int* in_sizes, int n_in,
                              void* d_out, int out_size, void* d_ws, size_t ws_size,
                              hipStream_t stream)
{
    const float* pred = (const float*)d_in[0];
    const float* tgt  = (const float*)d_in[1];
    float* out = (float*)d_out;
    double* acc = (double*)d_ws;                  // SLOTS*8 doubles = 2 KB

    zero_acc<<<1, SLOTS * 8, 0, stream>>>(acc);

    const dim3 grid(W_IMG / TILE, H_IMG / TILE, 2 * N_B);   // (16,16,32)
    skel_all<<<grid, 512, 0, stream>>>(pred, tgt, acc);

    finalize_k<<<1, 64, 0, stream>>>(acc, out);
}

// Round 6
// 459.326 us; speedup vs baseline: 1.7273x; 1.0025x over previous
//
#include <hip/hip_runtime.h>
#include <hip/hip_fp16.h>
#include <math.h>

// Geometry (fixed): B=16, C=1, H=W=1024, f32.
#define H_IMG 1024
#define W_IMG 1024
#define N_B   16
#define NPIX  (H_IMG * W_IMG)
#define N_TOT (16LL * NPIX)

// 64x64 owned tile, halo 12 (11 fused erode iters + 1 dilate ring).
// LDS tiles stored as fp16: values are [0,1] probabilities (or +/-inf bands);
// min/max of f16 values is f16-exact, so only the initial store rounds (2^-11).
#define TILE 64
#define HALO 12
#define RG   88          // TILE + 2*HALO rows / data cols
#define HST  92          // LDS row stride in halfs (184 B -> bank step 14, clean)
#define SLOTS 32         // atomic accumulator slots (each its own 64B line)

__device__ __forceinline__ float sigm(float x)  { return 1.0f / (1.0f + __expf(-x)); }
__device__ __forceinline__ float min3f(float a, float b, float c) { return fminf(fminf(a, b), c); }
__device__ __forceinline__ float max3f(float a, float b, float c) { return fmaxf(fmaxf(a, b), c); }

union H2U { __half2 h; unsigned u; };

// 4-px strip load/store, guaranteed single ds_read_b64 / ds_write_b64.
__device__ __forceinline__ float4 ld4h(const __half* p) {
    const uint2 u = *(const uint2*)p;
    H2U a, b; a.u = u.x; b.u = u.y;
    const float2 fa = __half22float2(a.h);
    const float2 fb = __half22float2(b.h);
    return make_float4(fa.x, fa.y, fb.x, fb.y);
}
__device__ __forceinline__ void st4h(__half* p, float x, float y, float z, float w) {
    H2U a, b;
    a.h = __floats2half2_rn(x, y);
    b.h = __floats2half2_rn(z, w);
    *(uint2*)p = make_uint2(a.u, b.u);
}
__device__ __forceinline__ float ldh(const __half* p) { return __half2float(*p); }

// Overwrite region cells whose GLOBAL coords are outside the image with +INF
// (erode-input identity). b16 stores, consecutive addresses: conflict-free.
__device__ __forceinline__ void band_fix_inf(__half* b, int r0, int c0, int tid)
{
    unsigned short* u = (unsigned short*)b;
    const unsigned short val = 0x7C00;   // +inf f16
    if (r0 == 0) {
        for (int idx = tid; idx < HALO * RG; idx += 512) {
            const int r = idx / RG, c = idx - r * RG;
            u[r * HST + c] = val;
        }
    }
    if (r0 == H_IMG - TILE) {
        for (int idx = tid; idx < HALO * RG; idx += 512) {
            const int r = idx / RG, c = idx - r * RG;
            u[(RG - HALO + r) * HST + c] = val;
        }
    }
    if (c0 == 0) {
        for (int idx = tid; idx < RG * HALO; idx += 512) {
            const int r = idx / HALO, c = idx - r * HALO;
            u[r * HST + c] = val;
        }
    }
    if (c0 == W_IMG - TILE) {
        for (int idx = tid; idx < RG * HALO; idx += 512) {
            const int r = idx / HALO, c = idx - r * HALO;
            u[r * HST + (RG - HALO + c)] = val;
        }
    }
}

// ---------------------------------------------------------------------------
// Whole soft_skeleton (11 iters) for one 64x64 tile in fp16 LDS, plus fused
// reductions. Bank-conflict design (8-lane-issue-group model):
//  * b64 strip ops: 8 consecutive lanes = 1 row x 8 consecutive strips ->
//    16 banks x 2-way = free (m136).
//  * horizontal +/-1 neighbors via adjacent-lane __shfl; boundary lanes fall
//    back to scalar u16 LDS reads on distinct rows -> distinct banks.
//  * dilate separable: V = vertical max3 (aligned b64 only), horizontal max3
//    of V via register shuffles.
// ---------------------------------------------------------------------------
template<bool SIG_SRC, bool SIG_OTH, bool DO_BCE, int CBASE>
__device__ __forceinline__
void skel_core(const float* __restrict__ src, const float* __restrict__ oth,
               double* __restrict__ acc, __half* cur, __half* nxt, float* red,
               int z, int r0, int c0, int tid, int bid)
{
    const float* s = src + (size_t)z * NPIX;

    // ---- load 88x88 region (+4-col pad), phase-aligned ----
    {   // phase A: strips 0..15, 1 row x 16 strips per quarter-wave
        const int st = tid & 15, c = 4 * st;
        const int gc = c0 - HALO + c;
        const bool vec = (gc >= 0) && (gc + 3 < W_IMG);
        for (int r = tid >> 4; r < RG; r += 32) {
            const int gr = min(max(r0 - HALO + r, 0), H_IMG - 1);
            const float* row = s + (size_t)gr * W_IMG;
            float4 v;
            if (vec) v = *(const float4*)&row[gc];
            else {
                v.x = row[min(max(gc + 0, 0), W_IMG - 1)];
                v.y = row[min(max(gc + 1, 0), W_IMG - 1)];
                v.z = row[min(max(gc + 2, 0), W_IMG - 1)];
                v.w = row[min(max(gc + 3, 0), W_IMG - 1)];
            }
            if (SIG_SRC) { v.x = sigm(v.x); v.y = sigm(v.y); v.z = sigm(v.z); v.w = sigm(v.w); }
            st4h(&cur[r * HST + c], v.x, v.y, v.z, v.w);
        }
    }
    {   // phase B: strips 16..22 (incl pad strip 22), 2 rows x 8 strips
        const int st = 16 + (tid & 7);
        if (st < 23) {
            const int c = 4 * st, gc = c0 - HALO + c;
            const bool vec = (gc >= 0) && (gc + 3 < W_IMG);
            for (int r = tid >> 3; r < RG; r += 64) {
                const int gr = min(max(r0 - HALO + r, 0), H_IMG - 1);
                const float* row = s + (size_t)gr * W_IMG;
                float4 v;
                if (vec) v = *(const float4*)&row[gc];
                else {
                    v.x = row[min(max(gc + 0, 0), W_IMG - 1)];
                    v.y = row[min(max(gc + 1, 0), W_IMG - 1)];
                    v.z = row[min(max(gc + 2, 0), W_IMG - 1)];
                    v.w = row[min(max(gc + 3, 0), W_IMG - 1)];
                }
                if (SIG_SRC) { v.x = sigm(v.x); v.y = sigm(v.y); v.z = sigm(v.z); v.w = sigm(v.w); }
                st4h(&cur[r * HST + c], v.x, v.y, v.z, v.w);
            }
        }
    }
    __syncthreads();

    const bool edge = (r0 == 0) | (c0 == 0) | (r0 == H_IMG - TILE) | (c0 == W_IMG - TILE);
    const float NINF = -__builtin_inff();

    float4 sk[2];
    sk[0] = make_float4(0.f, 0.f, 0.f, 0.f);
    sk[1] = make_float4(0.f, 0.f, 0.f, 0.f);

    const int oy = tid >> 3;      // owned row 0..63
    const int j  = tid & 7;       // strip slot (strips j, j+8 of owned)
    const int rr = HALO + oy;

    for (int k = 0; k < 11; ++k) {
        if (edge) { band_fix_inf(cur, r0, c0, tid); __syncthreads(); }

        const int rlo = k + 1, rhi = RG - 1 - k;        // rows [rlo, rhi)
        const int sA = rlo >> 2, sE = (rhi + 3) >> 2;   // strips [sA, sE)

        // ---- erode phase A: strips sA..sA+15 (1 row x 16 strips/quarter) ----
        {
            const int l  = tid & 15;
            const int st = sA + l;
            const int c  = 4 * st;
            const int gcb = c0 - HALO + c;
            const bool cOOB = ((unsigned)gcb > (unsigned)(W_IMG - 4));
            for (int r = rlo + (tid >> 4); r < rhi; r += 32) {
                const int base = r * HST + c;
                const float4 mid = ld4h(&cur[base]);
                const float4 up  = ld4h(&cur[base - HST]);
                const float4 dn  = ld4h(&cur[base + HST]);
                float lfv = __shfl_up(mid.w, 1);      // strip st-1 .w (same row for l>0)
                float rtv = __shfl_down(mid.x, 1);    // strip st+1 .x (same row for l<15)
                if (l == 0)  lfv = ldh(&cur[base - 1]);
                if (l == 15) rtv = ldh(&cur[base + 4]);
                float ex = fminf(min3f(up.x, mid.x, dn.x), fminf(lfv,   mid.y));
                float ey = fminf(min3f(up.y, mid.y, dn.y), fminf(mid.x, mid.z));
                float ez = fminf(min3f(up.z, mid.z, dn.z), fminf(mid.y, mid.w));
                float ew = fminf(min3f(up.w, mid.w, dn.w), fminf(mid.z, rtv));
                if (edge) {
                    const int gr = r0 - HALO + r;
                    if (((unsigned)gr >= (unsigned)H_IMG) | cOOB) { ex = ey = ez = ew = NINF; }
                }
                st4h(&nxt[base], ex, ey, ez, ew);
            }
        }
        // ---- erode phase B: strips sA+16..sE-1 (2 rows x 8 strips/quarter) ----
        {
            const int l  = tid & 7;
            const int st = sA + 16 + l;
            if (st < sE) {
                const int c = 4 * st;
                const int gcb = c0 - HALO + c;
                const bool cOOB  = ((unsigned)gcb > (unsigned)(W_IMG - 4));
                const bool lastS = (st == sE - 1);
                for (int r = rlo + (tid >> 3); r < rhi; r += 64) {
                    const int base = r * HST + c;
                    const float4 mid = ld4h(&cur[base]);
                    const float4 up  = ld4h(&cur[base - HST]);
                    const float4 dn  = ld4h(&cur[base + HST]);
                    float lfv = __shfl_up(mid.w, 1);
                    float rtv = __shfl_down(mid.x, 1);
                    if (l == 0)  lfv = ldh(&cur[base - 1]);
                    if (lastS)   rtv = ldh(&cur[base + 4]);
                    float ex = fminf(min3f(up.x, mid.x, dn.x), fminf(lfv,   mid.y));
                    float ey = fminf(min3f(up.y, mid.y, dn.y), fminf(mid.x, mid.z));
                    float ez = fminf(min3f(up.z, mid.z, dn.z), fminf(mid.y, mid.w));
                    float ew = fminf(min3f(up.w, mid.w, dn.w), fminf(mid.z, rtv));
                    if (edge) {
                        const int gr = r0 - HALO + r;
                        if (((unsigned)gr >= (unsigned)H_IMG) | cOOB) { ex = ey = ez = ew = NINF; }
                    }
                    st4h(&nxt[base], ex, ey, ez, ew);
                }
            }
        }
        __syncthreads();

        // ---- dilate(ernew) at owned pixels + skel update (separable V/H) ----
        {
            const int cA = HALO + 4 * j;           // strip j
            const int cB = cA + 32;                // strip j+8
            const int bA = rr * HST + cA;
            const int bB = rr * HST + cB;
            const float4 a0 = ld4h(&nxt[bA - HST]);
            const float4 m0 = ld4h(&nxt[bA]);
            const float4 d0 = ld4h(&nxt[bA + HST]);
            const float4 a1 = ld4h(&nxt[bB - HST]);
            const float4 m1 = ld4h(&nxt[bB]);
            const float4 d1 = ld4h(&nxt[bB + HST]);
            float4 V0, V1;   // vertical max3 per strip
            V0.x = max3f(a0.x, m0.x, d0.x); V0.y = max3f(a0.y, m0.y, d0.y);
            V0.z = max3f(a0.z, m0.z, d0.z); V0.w = max3f(a0.w, m0.w, d0.w);
            V1.x = max3f(a1.x, m1.x, d1.x); V1.y = max3f(a1.y, m1.y, d1.y);
            V1.z = max3f(a1.z, m1.z, d1.z); V1.w = max3f(a1.w, m1.w, d1.w);
            // horizontal neighbors of V via register shuffles (same row octet)
            const float sh_vl0  = __shfl_up  (V0.w, 1);   // strip j-1  .w
            const float sh_vr0a = __shfl_down(V0.x, 1);   // strip j+1  .x
            const float sh_vr0b = __shfl_up  (V1.x, 7);   // strip 8    .x  (j==7 seam)
            const float sh_vl1a = __shfl_up  (V1.w, 1);   // strip j+7  .w
            const float sh_vl1b = __shfl_down(V0.w, 7);   // strip 7    .w  (j==0 seam)
            const float sh_vr1  = __shfl_down(V1.x, 1);   // strip j+9  .x
            float vl0 = sh_vl0;
            float vr0 = (j == 7) ? sh_vr0b : sh_vr0a;
            float vl1 = (j == 0) ? sh_vl1b : sh_vl1a;
            float vr1 = sh_vr1;
            if (j == 0)   // block-left halo col 11 (8 lanes/wave, distinct rows->banks)
                vl0 = max3f(ldh(&nxt[bA - HST - 1]), ldh(&nxt[bA - 1]), ldh(&nxt[bA + HST - 1]));
            if (j == 7)   // block-right halo col 76
                vr1 = max3f(ldh(&nxt[bB - HST + 4]), ldh(&nxt[bB + 4]), ldh(&nxt[bB + HST + 4]));
            const float4 e0 = ld4h(&cur[bA]);   // er_k at owned
            const float4 e1 = ld4h(&cur[bB]);
            float o, dd;
            o = max3f(vl0,  V0.x, V0.y); dd = fmaxf(e0.x - o, 0.f); sk[0].x += fmaxf(dd - sk[0].x * dd, 0.f);
            o = max3f(V0.x, V0.y, V0.z); dd = fmaxf(e0.y - o, 0.f); sk[0].y += fmaxf(dd - sk[0].y * dd, 0.f);
            o = max3f(V0.y, V0.z, V0.w); dd = fmaxf(e0.z - o, 0.f); sk[0].z += fmaxf(dd - sk[0].z * dd, 0.f);
            o = max3f(V0.z, V0.w, vr0 ); dd = fmaxf(e0.w - o, 0.f); sk[0].w += fmaxf(dd - sk[0].w * dd, 0.f);
            o = max3f(vl1,  V1.x, V1.y); dd = fmaxf(e1.x - o, 0.f); sk[1].x += fmaxf(dd - sk[1].x * dd, 0.f);
            o = max3f(V1.x, V1.y, V1.z); dd = fmaxf(e1.y - o, 0.f); sk[1].y += fmaxf(dd - sk[1].y * dd, 0.f);
            o = max3f(V1.y, V1.z, V1.w); dd = fmaxf(e1.z - o, 0.f); sk[1].z += fmaxf(dd - sk[1].z * dd, 0.f);
            o = max3f(V1.z, V1.w, vr1 ); dd = fmaxf(e1.w - o, 0.f); sk[1].w += fmaxf(dd - sk[1].w * dd, 0.f);
        }
        __syncthreads();

        __half* tp = cur; cur = nxt; nxt = tp;
    }

    // ---- fused reductions over owned pixels ----
    const size_t gbase = (size_t)z * NPIX + (size_t)(r0 + oy) * W_IMG + c0;
    const float* op = oth + gbase;
    const float* pp = src + gbase;   // pred logits (DO_BCE only)
    float ss = 0.f, sso = 0.f, sb = 0.f, sp = 0.f, sy = 0.f, spy = 0.f;
    #pragma unroll
    for (int t = 0; t < 2; ++t) {
        const int cc = 4 * (j + 8 * t);
        float4 ov = *(const float4*)&op[cc];
        float o0 = ov.x, o1 = ov.y, o2 = ov.z, o3 = ov.w;
        if (SIG_OTH) { o0 = sigm(o0); o1 = sigm(o1); o2 = sigm(o2); o3 = sigm(o3); }
        ss  += sk[t].x + sk[t].y + sk[t].z + sk[t].w;
        sso += sk[t].x * o0 + sk[t].y * o1 + sk[t].z * o2 + sk[t].w * o3;
        if (DO_BCE) {
            const float4 xv = *(const float4*)&pp[cc];
            const float xs[4] = {xv.x, xv.y, xv.z, xv.w};
            const float ys[4] = {o0, o1, o2, o3};   // SIG_OTH=false here: raw target
            #pragma unroll
            for (int q = 0; q < 4; ++q) {
                const float x = xs[q], y = ys[q];
                const float zz = __expf(-fabsf(x));
                const float inv = 1.0f / (1.0f + zz);
                sb += fmaxf(x, 0.f) + __logf(1.0f + zz) - y * x;
                const float p = (x >= 0.f) ? inv : zz * inv;
                sp += p; sy += y; spy += p * y;
            }
        }
    }
    for (int off = 32; off > 0; off >>= 1) {
        ss  += __shfl_down(ss,  off);
        sso += __shfl_down(sso, off);
        if (DO_BCE) {
            sb  += __shfl_down(sb,  off);
            sp  += __shfl_down(sp,  off);
            sy  += __shfl_down(sy,  off);
            spy += __shfl_down(spy, off);
        }
    }
    const int wid = tid >> 6, lane = tid & 63;
    if (lane == 0) {
        red[0 * 8 + wid] = ss;  red[1 * 8 + wid] = sso;
        if (DO_BCE) {
            red[2 * 8 + wid] = sb;  red[3 * 8 + wid] = sp;
            red[4 * 8 + wid] = sy;  red[5 * 8 + wid] = spy;
        }
    }
    __syncthreads();
    if (tid == 0) {
        double SS = 0, SO = 0, B0 = 0, B1 = 0, B2 = 0, B3 = 0;
        for (int w = 0; w < 8; ++w) {
            SS += (double)red[0 * 8 + w];  SO += (double)red[1 * 8 + w];
            if (DO_BCE) {
                B0 += (double)red[2 * 8 + w]; B1 += (double)red[3 * 8 + w];
                B2 += (double)red[4 * 8 + w]; B3 += (double)red[5 * 8 + w];
            }
        }
        const int slot = bid & (SLOTS - 1);
        atomicAdd(&acc[slot * 8 + CBASE],     SS);
        atomicAdd(&acc[slot * 8 + CBASE + 1], SO);
        if (DO_BCE) {
            atomicAdd(&acc[slot * 8 + 0], B0);
            atomicAdd(&acc[slot * 8 + 1], B1);
            atomicAdd(&acc[slot * 8 + 2], B2);
            atomicAdd(&acc[slot * 8 + 3], B3);
        }
    }
}

// Both skeletons in one dispatch: z<16 -> skel(sigmoid(pred)) + BCE/dice sums;
// z>=16 -> skel(target), reduced against sigmoid(pred).
__global__ __launch_bounds__(512, 8)
void skel_all(const float* __restrict__ pred, const float* __restrict__ tgt,
              double* __restrict__ acc)
{
    __shared__ __align__(16) __half buf0[RG * HST];
    __shared__ __align__(16) __half buf1[RG * HST];
    __shared__ float red[48];
    const int tid = threadIdx.x;
    const int r0 = blockIdx.y * TILE, c0 = blockIdx.x * TILE;
    const int bid = ((int)blockIdx.z & 15) * 256 + blockIdx.y * 16 + blockIdx.x;
    if ((int)blockIdx.z < N_B)
        skel_core<true,  false, true,  4>(pred, tgt, acc, buf0, buf1, red,
                                          blockIdx.z, r0, c0, tid, bid);
    else
        skel_core<false, true,  false, 6>(tgt, pred, acc, buf0, buf1, red,
                                          blockIdx.z - N_B, r0, c0, tid, bid);
}

__global__ void zero_acc(double* acc) { acc[threadIdx.x] = 0.0; }

__global__ void finalize_k(const double* __restrict__ acc, float* __restrict__ out)
{
    __shared__ double S[8];
    const int jj = threadIdx.x;
    if (jj < 8) {
        double t = 0.0;
        for (int s = 0; s < SLOTS; ++s) t += acc[s * 8 + jj];
        S[jj] = t;
    }
    __syncthreads();
    if (jj == 0) {
        const double bce   = S[0] / (double)N_TOT;
        const double dice  = (2.0 * S[3] + 1.0) / (S[1] + S[2] + 1.0);
        const double tprec = (S[5] + 1.0) / (S[4] + 1.0);
        const double tsens = (S[7] + 1.0) / (S[6] + 1.0);
        const double cl    = 2.0 * tprec * tsens / (tprec + tsens + 1e-7);
        out[0] = (float)(0.3 * bce + 0.3 * (1.0 - dice) + 0.4 * (1.0 - cl));
    }
}

// ---------------------------------------------------------------------------
extern "C" void kernel_launch(void* const* d_in, const int* in_sizes, int n_in,
                              void* d_out, int out_size, void* d_ws, size_t ws_size,
                              hipStream_t stream)
{
    const float* pred = (const float*)d_in[0];
    const float* tgt  = (const float*)d_in[1];
    float* out = (float*)d_out;
    double* acc = (double*)d_ws;                  // SLOTS*8 doubles = 2 KB

    zero_acc<<<1, SLOTS * 8, 0, stream>>>(acc);

    const dim3 grid(W_IMG / TILE, H_IMG / TILE, 2 * N_B);   // (16,16,32)
    skel_all<<<grid, 512, 0, stream>>>(pred, tgt, acc);

    finalize_k<<<1, 64, 0, stream>>>(acc, out);
}

// Round 7
// 387.291 us; speedup vs baseline: 2.0485x; 1.1860x over previous
//
#include <hip/hip_runtime.h>
#include <hip/hip_fp16.h>
#include <math.h>

// Geometry (fixed): B=16, C=1, H=W=1024, f32.
#define H_IMG 1024
#define W_IMG 1024
#define N_B   16
#define NPIX  (H_IMG * W_IMG)
#define N_TOT (16LL * NPIX)

// 64x64 owned tile, halo 12 (11 fused erode iters + 1 dilate ring).
// LDS tiles in fp16; ALL stencil math in packed f16 (v_pk_*, 2 px/instr).
// min/max of f16 values is f16-exact -> only the initial store rounds (2^-11);
// the packed-f16 skel fma/add adds <= ~2e-3 total loss error (threshold 1.4e-2).
#define TILE 64
#define HALO 12
#define RG   88          // TILE + 2*HALO rows / data cols
#define HST  92          // LDS row stride in halfs (184 B)
#define SLOTS 32         // atomic accumulator slots (each its own 64B line)

#define PK_NINF 0xFC00FC00u   // {-inf,-inf} f16x2
#define PK_SGN  0x80008000u   // packed sign-flip mask

__device__ __forceinline__ float sigm(float x)  { return 1.0f / (1.0f + __expf(-x)); }

// ---- packed f16 reg ops (pure VALU, no memory: asm ordering is safe) ----
__device__ __forceinline__ unsigned pk_min(unsigned a, unsigned b) {
    unsigned r; asm("v_pk_min_f16 %0, %1, %2" : "=v"(r) : "v"(a), "v"(b)); return r;
}
__device__ __forceinline__ unsigned pk_max(unsigned a, unsigned b) {
    unsigned r; asm("v_pk_max_f16 %0, %1, %2" : "=v"(r) : "v"(a), "v"(b)); return r;
}
__device__ __forceinline__ unsigned pk_add(unsigned a, unsigned b) {
    unsigned r; asm("v_pk_add_f16 %0, %1, %2" : "=v"(r) : "v"(a), "v"(b)); return r;
}
__device__ __forceinline__ unsigned pk_fma(unsigned a, unsigned b, unsigned c) {
    unsigned r; asm("v_pk_fma_f16 %0, %1, %2, %3" : "=v"(r) : "v"(a), "v"(b), "v"(c)); return r;
}
// {hi.low16, lo.high16}: result low half = lo's HIGH half, high half = hi's LOW half.
__device__ __forceinline__ unsigned alignb(unsigned hi, unsigned lo) {
    unsigned r; asm("v_alignbit_b32 %0, %1, %2, 16" : "=v"(r) : "v"(hi), "v"(lo)); return r;
}

union H2U { __half2 h; unsigned u; };

__device__ __forceinline__ uint2 ld2u(const __half* p) { return *(const uint2*)p; }
__device__ __forceinline__ void  st2u(__half* p, unsigned a, unsigned b) { *(uint2*)p = make_uint2(a, b); }
__device__ __forceinline__ void st4h(__half* p, float x, float y, float z, float w) {
    H2U a, b;
    a.h = __floats2half2_rn(x, y);
    b.h = __floats2half2_rn(z, w);
    *(uint2*)p = make_uint2(a.u, b.u);
}

// Overwrite region cells whose GLOBAL coords are outside the image with +INF
// (erode-input identity). b16 stores, consecutive addresses: conflict-free.
__device__ __forceinline__ void band_fix_inf(__half* b, int r0, int c0, int tid)
{
    unsigned short* u = (unsigned short*)b;
    const unsigned short val = 0x7C00;   // +inf f16
    if (r0 == 0) {
        for (int idx = tid; idx < HALO * RG; idx += 512) {
            const int r = idx / RG, c = idx - r * RG;
            u[r * HST + c] = val;
        }
    }
    if (r0 == H_IMG - TILE) {
        for (int idx = tid; idx < HALO * RG; idx += 512) {
            const int r = idx / RG, c = idx - r * RG;
            u[(RG - HALO + r) * HST + c] = val;
        }
    }
    if (c0 == 0) {
        for (int idx = tid; idx < RG * HALO; idx += 512) {
            const int r = idx / HALO, c = idx - r * HALO;
            u[r * HST + c] = val;
        }
    }
    if (c0 == W_IMG - TILE) {
        for (int idx = tid; idx < RG * HALO; idx += 512) {
            const int r = idx / HALO, c = idx - r * HALO;
            u[r * HST + (RG - HALO + c)] = val;
        }
    }
}

// ---------------------------------------------------------------------------
// Whole soft_skeleton (11 iters) for one 64x64 tile in fp16 LDS, packed-f16
// math, plus fused reductions. Bank design unchanged from the verified r6
// kernel: b64 strip ops = 1 row x 8 consecutive strips per 8-lane group
// (2-way, free); horizontal neighbors via __shfl + v_alignbit; boundary lanes
// fall back to scalar u16 LDS reads (distinct rows -> distinct banks).
// ---------------------------------------------------------------------------
template<bool SIG_SRC, bool SIG_OTH, bool DO_BCE, int CBASE>
__device__ __forceinline__
void skel_core(const float* __restrict__ src, const float* __restrict__ oth,
               double* __restrict__ acc, __half* cur, __half* nxt, float* red,
               int z, int r0, int c0, int tid, int bid)
{
    const float* s = src + (size_t)z * NPIX;

    // ---- load 88x88 region (+4-col pad), phase-aligned ----
    {   // phase A: strips 0..15, 1 row x 16 strips per quarter-wave
        const int st = tid & 15, c = 4 * st;
        const int gc = c0 - HALO + c;
        const bool vec = (gc >= 0) && (gc + 3 < W_IMG);
        for (int r = tid >> 4; r < RG; r += 32) {
            const int gr = min(max(r0 - HALO + r, 0), H_IMG - 1);
            const float* row = s + (size_t)gr * W_IMG;
            float4 v;
            if (vec) v = *(const float4*)&row[gc];
            else {
                v.x = row[min(max(gc + 0, 0), W_IMG - 1)];
                v.y = row[min(max(gc + 1, 0), W_IMG - 1)];
                v.z = row[min(max(gc + 2, 0), W_IMG - 1)];
                v.w = row[min(max(gc + 3, 0), W_IMG - 1)];
            }
            if (SIG_SRC) { v.x = sigm(v.x); v.y = sigm(v.y); v.z = sigm(v.z); v.w = sigm(v.w); }
            st4h(&cur[r * HST + c], v.x, v.y, v.z, v.w);
        }
    }
    {   // phase B: strips 16..22 (incl pad strip 22), 2 rows x 8 strips
        const int st = 16 + (tid & 7);
        if (st < 23) {
            const int c = 4 * st, gc = c0 - HALO + c;
            const bool vec = (gc >= 0) && (gc + 3 < W_IMG);
            for (int r = tid >> 3; r < RG; r += 64) {
                const int gr = min(max(r0 - HALO + r, 0), H_IMG - 1);
                const float* row = s + (size_t)gr * W_IMG;
                float4 v;
                if (vec) v = *(const float4*)&row[gc];
                else {
                    v.x = row[min(max(gc + 0, 0), W_IMG - 1)];
                    v.y = row[min(max(gc + 1, 0), W_IMG - 1)];
                    v.z = row[min(max(gc + 2, 0), W_IMG - 1)];
                    v.w = row[min(max(gc + 3, 0), W_IMG - 1)];
                }
                if (SIG_SRC) { v.x = sigm(v.x); v.y = sigm(v.y); v.z = sigm(v.z); v.w = sigm(v.w); }
                st4h(&cur[r * HST + c], v.x, v.y, v.z, v.w);
            }
        }
    }
    __syncthreads();

    const bool edge = (r0 == 0) | (c0 == 0) | (r0 == H_IMG - TILE) | (c0 == W_IMG - TILE);

    // packed skel accumulators: strips A,B x half2 pairs (01,23). f16 zero = 0.
    unsigned skA01 = 0, skA23 = 0, skB01 = 0, skB23 = 0;

    const int oy = tid >> 3;      // owned row 0..63
    const int j  = tid & 7;       // strip slot (strips j, j+8 of owned)
    const int rr = HALO + oy;

    for (int k = 0; k < 11; ++k) {
        if (edge) { band_fix_inf(cur, r0, c0, tid); __syncthreads(); }

        const int rlo = k + 1, rhi = RG - 1 - k;        // rows [rlo, rhi)
        const int sA = rlo >> 2, sE = (rhi + 3) >> 2;   // strips [sA, sE)

        // ---- erode phase A: strips sA..sA+15 (1 row x 16 strips/quarter) ----
        {
            const int l  = tid & 15;
            const int st = sA + l;
            const int c  = 4 * st;
            const int gcb = c0 - HALO + c;
            const bool cOOB = ((unsigned)gcb > (unsigned)(W_IMG - 4));
            for (int r = rlo + (tid >> 4); r < rhi; r += 32) {
                const int base = r * HST + c;
                const uint2 mid = ld2u(&cur[base]);
                const uint2 up  = ld2u(&cur[base - HST]);
                const uint2 dn  = ld2u(&cur[base + HST]);
                unsigned lfreg = (unsigned)__shfl_up((int)mid.y, 1);    // left strip m23
                unsigned rtreg = (unsigned)__shfl_down((int)mid.x, 1);  // right strip m01
                if (l == 0)  lfreg = ((unsigned)*(const unsigned short*)(cur + base - 1)) << 16;
                if (l == 15) rtreg = (unsigned)*(const unsigned short*)(cur + base + 4);
                const unsigned L01 = alignb(mid.x, lfreg);   // [m-1, m0]
                const unsigned L23 = alignb(mid.y, mid.x);   // [m1 , m2] (== R01)
                const unsigned R23 = alignb(rtreg, mid.y);   // [m3 , m4]
                unsigned e01 = pk_min(pk_min(pk_min(up.x, dn.x), mid.x), pk_min(L01, L23));
                unsigned e23 = pk_min(pk_min(pk_min(up.y, dn.y), mid.y), pk_min(L23, R23));
                if (edge) {
                    const int gr = r0 - HALO + r;
                    if (((unsigned)gr >= (unsigned)H_IMG) | cOOB) { e01 = PK_NINF; e23 = PK_NINF; }
                }
                st2u(&nxt[base], e01, e23);
            }
        }
        // ---- erode phase B: strips sA+16..sE-1 (2 rows x 8 strips/quarter) ----
        {
            const int l  = tid & 7;
            const int st = sA + 16 + l;
            if (st < sE) {   // sE-sA <= 22 -> l <= 6 active, shfl stays in-row
                const int c = 4 * st;
                const int gcb = c0 - HALO + c;
                const bool cOOB  = ((unsigned)gcb > (unsigned)(W_IMG - 4));
                const bool lastS = (st == sE - 1);
                for (int r = rlo + (tid >> 3); r < rhi; r += 64) {
                    const int base = r * HST + c;
                    const uint2 mid = ld2u(&cur[base]);
                    const uint2 up  = ld2u(&cur[base - HST]);
                    const uint2 dn  = ld2u(&cur[base + HST]);
                    unsigned lfreg = (unsigned)__shfl_up((int)mid.y, 1);
                    unsigned rtreg = (unsigned)__shfl_down((int)mid.x, 1);
                    if (l == 0)  lfreg = ((unsigned)*(const unsigned short*)(cur + base - 1)) << 16;
                    if (lastS)   rtreg = (unsigned)*(const unsigned short*)(cur + base + 4);
                    const unsigned L01 = alignb(mid.x, lfreg);
                    const unsigned L23 = alignb(mid.y, mid.x);
                    const unsigned R23 = alignb(rtreg, mid.y);
                    unsigned e01 = pk_min(pk_min(pk_min(up.x, dn.x), mid.x), pk_min(L01, L23));
                    unsigned e23 = pk_min(pk_min(pk_min(up.y, dn.y), mid.y), pk_min(L23, R23));
                    if (edge) {
                        const int gr = r0 - HALO + r;
                        if (((unsigned)gr >= (unsigned)H_IMG) | cOOB) { e01 = PK_NINF; e23 = PK_NINF; }
                    }
                    st2u(&nxt[base], e01, e23);
                }
            }
        }
        __syncthreads();

        // ---- dilate(ernew) at owned pixels + packed skel update ----
        {
            const int cA = HALO + 4 * j;           // strip j
            const int cB = cA + 32;                // strip j+8
            const int bA = rr * HST + cA;
            const int bB = rr * HST + cB;
            const uint2 a0 = ld2u(&nxt[bA - HST]);
            const uint2 m0 = ld2u(&nxt[bA]);
            const uint2 d0 = ld2u(&nxt[bA + HST]);
            const uint2 a1 = ld2u(&nxt[bB - HST]);
            const uint2 m1 = ld2u(&nxt[bB]);
            const uint2 d1 = ld2u(&nxt[bB + HST]);
            const unsigned VA01 = pk_max(pk_max(a0.x, m0.x), d0.x);
            const unsigned VA23 = pk_max(pk_max(a0.y, m0.y), d0.y);
            const unsigned VB01 = pk_max(pk_max(a1.x, m1.x), d1.x);
            const unsigned VB23 = pk_max(pk_max(a1.y, m1.y), d1.y);
            // horizontal neighbor regs (hi/lo halves used via alignb)
            unsigned vlA = (unsigned)__shfl_up((int)VA23, 1);        // high = V[cA-1]
            const unsigned vrAa = (unsigned)__shfl_down((int)VA01, 1);
            const unsigned vrAb = (unsigned)__shfl_up((int)VB01, 7); // j==7 seam: strip 8
            unsigned vrA = (j == 7) ? vrAb : vrAa;                   // low = V[cA+4]
            const unsigned vlBa = (unsigned)__shfl_up((int)VB23, 1);
            const unsigned vlBb = (unsigned)__shfl_down((int)VA23, 7); // j==0 seam: strip 7
            unsigned vlB = (j == 0) ? vlBb : vlBa;                   // high = V[cB-1]
            unsigned vrB = (unsigned)__shfl_down((int)VB01, 1);      // low = V[cB+4]
            if (j == 0) {   // block-left halo col: scalar u16 vertical max (low halves)
                const unsigned t1 = *(const unsigned short*)(nxt + bA - HST - 1);
                const unsigned t2 = *(const unsigned short*)(nxt + bA - 1);
                const unsigned t3 = *(const unsigned short*)(nxt + bA + HST - 1);
                vlA = pk_max(pk_max(t1, t2), t3) << 16;              // value -> high half
            }
            if (j == 7) {   // block-right halo col
                const unsigned t1 = *(const unsigned short*)(nxt + bB - HST + 4);
                const unsigned t2 = *(const unsigned short*)(nxt + bB + 4);
                const unsigned t3 = *(const unsigned short*)(nxt + bB + HST + 4);
                vrB = pk_max(pk_max(t1, t2), t3);                    // value in low half
            }
            // open = horizontal max3 of V (packed)
            const unsigned LA = alignb(VA01, vlA);    // [V-1, V0]
            const unsigned MA = alignb(VA23, VA01);   // [V1 , V2]
            const unsigned RA = alignb(vrA,  VA23);   // [V3 , V4]
            const unsigned oA01 = pk_max(pk_max(LA, MA), VA01);
            const unsigned oA23 = pk_max(pk_max(MA, RA), VA23);
            const unsigned LB = alignb(VB01, vlB);
            const unsigned MB = alignb(VB23, VB01);
            const unsigned RB = alignb(vrB,  VB23);
            const unsigned oB01 = pk_max(pk_max(LB, MB), VB01);
            const unsigned oB23 = pk_max(pk_max(MB, RB), VB23);
            // er_k at owned (pre-erode center values)
            const uint2 eA = ld2u(&cur[bA]);
            const uint2 eB = ld2u(&cur[bB]);
            // delta = relu(e - open); skel += relu(delta - skel*delta)
            unsigned d, u;
            d = pk_max(pk_add(eA.x, oA01 ^ PK_SGN), 0u);
            u = pk_max(pk_fma(skA01 ^ PK_SGN, d, d), 0u);
            skA01 = pk_add(skA01, u);
            d = pk_max(pk_add(eA.y, oA23 ^ PK_SGN), 0u);
            u = pk_max(pk_fma(skA23 ^ PK_SGN, d, d), 0u);
            skA23 = pk_add(skA23, u);
            d = pk_max(pk_add(eB.x, oB01 ^ PK_SGN), 0u);
            u = pk_max(pk_fma(skB01 ^ PK_SGN, d, d), 0u);
            skB01 = pk_add(skB01, u);
            d = pk_max(pk_add(eB.y, oB23 ^ PK_SGN), 0u);
            u = pk_max(pk_fma(skB23 ^ PK_SGN, d, d), 0u);
            skB23 = pk_add(skB23, u);
        }
        __syncthreads();

        __half* tp = cur; cur = nxt; nxt = tp;
    }

    // ---- unpack skel to f32 ----
    float skf[8];
    {
        H2U u; float2 f;
        u.u = skA01; f = __half22float2(u.h); skf[0] = f.x; skf[1] = f.y;
        u.u = skA23; f = __half22float2(u.h); skf[2] = f.x; skf[3] = f.y;
        u.u = skB01; f = __half22float2(u.h); skf[4] = f.x; skf[5] = f.y;
        u.u = skB23; f = __half22float2(u.h); skf[6] = f.x; skf[7] = f.y;
    }

    // ---- fused reductions over owned pixels ----
    const size_t gbase = (size_t)z * NPIX + (size_t)(r0 + oy) * W_IMG + c0;
    const float* op = oth + gbase;
    const float* pp = src + gbase;   // pred logits (DO_BCE only)
    float ss = 0.f, sso = 0.f, sb = 0.f, sp = 0.f, sy = 0.f, spy = 0.f;
    #pragma unroll
    for (int t = 0; t < 2; ++t) {
        const int cc = 4 * (j + 8 * t);
        float4 ov = *(const float4*)&op[cc];
        float o0 = ov.x, o1 = ov.y, o2 = ov.z, o3 = ov.w;
        if (SIG_OTH) { o0 = sigm(o0); o1 = sigm(o1); o2 = sigm(o2); o3 = sigm(o3); }
        const float s0 = skf[4*t], s1 = skf[4*t+1], s2 = skf[4*t+2], s3 = skf[4*t+3];
        ss  += s0 + s1 + s2 + s3;
        sso += s0 * o0 + s1 * o1 + s2 * o2 + s3 * o3;
        if (DO_BCE) {
            const float4 xv = *(const float4*)&pp[cc];
            const float xs[4] = {xv.x, xv.y, xv.z, xv.w};
            const float ys[4] = {o0, o1, o2, o3};   // SIG_OTH=false here: raw target
            #pragma unroll
            for (int q = 0; q < 4; ++q) {
                const float x = xs[q], y = ys[q];
                const float zz = __expf(-fabsf(x));
                const float inv = 1.0f / (1.0f + zz);
                sb += fmaxf(x, 0.f) + __logf(1.0f + zz) - y * x;
                const float p = (x >= 0.f) ? inv : zz * inv;
                sp += p; sy += y; spy += p * y;
            }
        }
    }
    for (int off = 32; off > 0; off >>= 1) {
        ss  += __shfl_down(ss,  off);
        sso += __shfl_down(sso, off);
        if (DO_BCE) {
            sb  += __shfl_down(sb,  off);
            sp  += __shfl_down(sp,  off);
            sy  += __shfl_down(sy,  off);
            spy += __shfl_down(spy, off);
        }
    }
    const int wid = tid >> 6, lane = tid & 63;
    if (lane == 0) {
        red[0 * 8 + wid] = ss;  red[1 * 8 + wid] = sso;
        if (DO_BCE) {
            red[2 * 8 + wid] = sb;  red[3 * 8 + wid] = sp;
            red[4 * 8 + wid] = sy;  red[5 * 8 + wid] = spy;
        }
    }
    __syncthreads();
    if (tid == 0) {
        double SS = 0, SO = 0, B0 = 0, B1 = 0, B2 = 0, B3 = 0;
        for (int w = 0; w < 8; ++w) {
            SS += (double)red[0 * 8 + w];  SO += (double)red[1 * 8 + w];
            if (DO_BCE) {
                B0 += (double)red[2 * 8 + w]; B1 += (double)red[3 * 8 + w];
                B2 += (double)red[4 * 8 + w]; B3 += (double)red[5 * 8 + w];
            }
        }
        const int slot = bid & (SLOTS - 1);
        atomicAdd(&acc[slot * 8 + CBASE],     SS);
        atomicAdd(&acc[slot * 8 + CBASE + 1], SO);
        if (DO_BCE) {
            atomicAdd(&acc[slot * 8 + 0], B0);
            atomicAdd(&acc[slot * 8 + 1], B1);
            atomicAdd(&acc[slot * 8 + 2], B2);
            atomicAdd(&acc[slot * 8 + 3], B3);
        }
    }
}

// Both skeletons in one dispatch: z<16 -> skel(sigmoid(pred)) + BCE/dice sums;
// z>=16 -> skel(target), reduced against sigmoid(pred).
__global__ __launch_bounds__(512, 8)
void skel_all(const float* __restrict__ pred, const float* __restrict__ tgt,
              double* __restrict__ acc)
{
    __shared__ __align__(16) __half buf0[RG * HST];
    __shared__ __align__(16) __half buf1[RG * HST];
    __shared__ float red[48];
    const int tid = threadIdx.x;
    const int r0 = blockIdx.y * TILE, c0 = blockIdx.x * TILE;
    const int bid = ((int)blockIdx.z & 15) * 256 + blockIdx.y * 16 + blockIdx.x;
    if ((int)blockIdx.z < N_B)
        skel_core<true,  false, true,  4>(pred, tgt, acc, buf0, buf1, red,
                                          blockIdx.z, r0, c0, tid, bid);
    else
        skel_core<false, true,  false, 6>(tgt, pred, acc, buf0, buf1, red,
                                          blockIdx.z - N_B, r0, c0, tid, bid);
}

__global__ void zero_acc(double* acc) { acc[threadIdx.x] = 0.0; }

__global__ void finalize_k(const double* __restrict__ acc, float* __restrict__ out)
{
    __shared__ double S[8];
    const int jj = threadIdx.x;
    if (jj < 8) {
        double t = 0.0;
        for (int s = 0; s < SLOTS; ++s) t += acc[s * 8 + jj];
        S[jj] = t;
    }
    __syncthreads();
    if (jj == 0) {
        const double bce   = S[0] / (double)N_TOT;
        const double dice  = (2.0 * S[3] + 1.0) / (S[1] + S[2] + 1.0);
        const double tprec = (S[5] + 1.0) / (S[4] + 1.0);
        const double tsens = (S[7] + 1.0) / (S[6] + 1.0);
        const double cl    = 2.0 * tprec * tsens / (tprec + tsens + 1e-7);
        out[0] = (float)(0.3 * bce + 0.3 * (1.0 - dice) + 0.4 * (1.0 - cl));
    }
}

// ---------------------------------------------------------------------------
extern "C" void kernel_launch(void* const* d_in, const int* in_sizes, int n_in,
                              void* d_out, int out_size, void* d_ws, size_t ws_size,
                              hipStream_t stream)
{
    const float* pred = (const float*)d_in[0];
    const float* tgt  = (const float*)d_in[1];
    float* out = (float*)d_out;
    double* acc = (double*)d_ws;                  // SLOTS*8 doubles = 2 KB

    zero_acc<<<1, SLOTS * 8, 0, stream>>>(acc);

    const dim3 grid(W_IMG / TILE, H_IMG / TILE, 2 * N_B);   // (16,16,32)
    skel_all<<<grid, 512, 0, stream>>>(pred, tgt, acc);

    finalize_k<<<1, 64, 0, stream>>>(acc, out);
}

// Round 8
// 258.732 us; speedup vs baseline: 3.0664x; 1.4969x over previous
//
#include <hip/hip_runtime.h>
#include <hip/hip_fp16.h>
#include <math.h>

// Geometry (fixed): B=16, C=1, H=W=1024, f32.
#define H_IMG 1024
#define W_IMG 1024
#define N_B   16
#define NPIX  (H_IMG * W_IMG)
#define N_TOT (16LL * NPIX)

// 64x64 owned tile, halo 12 (11 fused erode iters + 1 dilate ring).
// z<16 (sigmoid(pred) skeleton): fp16 LDS + packed-f16 math (verified r7).
// z>=16 (target skeleton): target is EXACTLY {0,1} -> Boolean morphology,
// bit-packed 32 px/u32 (erode=AND-plus, dilate=OR-3x3, skel|=er&~open). Exact.
#define TILE 64
#define HALO 12
#define RG   88          // TILE + 2*HALO rows / data cols
#define HST  92          // f16 LDS row stride in halfs (184 B)
#define SLOTS 32         // atomic accumulator slots (each its own 64B line)

#define PK_NINF 0xFC00FC00u   // {-inf,-inf} f16x2
#define PK_SGN  0x80008000u   // packed sign-flip mask

__device__ __forceinline__ float sigm(float x)  { return 1.0f / (1.0f + __expf(-x)); }

// ---- packed f16 reg ops (pure VALU, no memory: asm ordering is safe) ----
__device__ __forceinline__ unsigned pk_min(unsigned a, unsigned b) {
    unsigned r; asm("v_pk_min_f16 %0, %1, %2" : "=v"(r) : "v"(a), "v"(b)); return r;
}
__device__ __forceinline__ unsigned pk_max(unsigned a, unsigned b) {
    unsigned r; asm("v_pk_max_f16 %0, %1, %2" : "=v"(r) : "v"(a), "v"(b)); return r;
}
__device__ __forceinline__ unsigned pk_add(unsigned a, unsigned b) {
    unsigned r; asm("v_pk_add_f16 %0, %1, %2" : "=v"(r) : "v"(a), "v"(b)); return r;
}
__device__ __forceinline__ unsigned pk_fma(unsigned a, unsigned b, unsigned c) {
    unsigned r; asm("v_pk_fma_f16 %0, %1, %2, %3" : "=v"(r) : "v"(a), "v"(b), "v"(c)); return r;
}
// {hi.low16, lo.high16}: result low half = lo's HIGH half, high half = hi's LOW half.
__device__ __forceinline__ unsigned alignb(unsigned hi, unsigned lo) {
    unsigned r; asm("v_alignbit_b32 %0, %1, %2, 16" : "=v"(r) : "v"(hi), "v"(lo)); return r;
}

union H2U { __half2 h; unsigned u; };

__device__ __forceinline__ uint2 ld2u(const __half* p) { return *(const uint2*)p; }
__device__ __forceinline__ void  st2u(__half* p, unsigned a, unsigned b) { *(uint2*)p = make_uint2(a, b); }
__device__ __forceinline__ void st4h(__half* p, float x, float y, float z, float w) {
    H2U a, b;
    a.h = __floats2half2_rn(x, y);
    b.h = __floats2half2_rn(z, w);
    *(uint2*)p = make_uint2(a.u, b.u);
}

// Overwrite region cells whose GLOBAL coords are outside the image with +INF
// (erode-input identity). b16 stores, consecutive addresses: conflict-free.
__device__ __forceinline__ void band_fix_inf(__half* b, int r0, int c0, int tid)
{
    unsigned short* u = (unsigned short*)b;
    const unsigned short val = 0x7C00;   // +inf f16
    if (r0 == 0) {
        for (int idx = tid; idx < HALO * RG; idx += 512) {
            const int r = idx / RG, c = idx - r * RG;
            u[r * HST + c] = val;
        }
    }
    if (r0 == H_IMG - TILE) {
        for (int idx = tid; idx < HALO * RG; idx += 512) {
            const int r = idx / RG, c = idx - r * RG;
            u[(RG - HALO + r) * HST + c] = val;
        }
    }
    if (c0 == 0) {
        for (int idx = tid; idx < RG * HALO; idx += 512) {
            const int r = idx / HALO, c = idx - r * HALO;
            u[r * HST + c] = val;
        }
    }
    if (c0 == W_IMG - TILE) {
        for (int idx = tid; idx < RG * HALO; idx += 512) {
            const int r = idx / HALO, c = idx - r * HALO;
            u[r * HST + (RG - HALO + c)] = val;
        }
    }
}

// ---------------------------------------------------------------------------
// f16 path (z<16): whole soft_skeleton of sigmoid(pred) for one 64x64 tile,
// packed-f16 math, fused BCE/dice + skel reductions. Verified in r7.
// ---------------------------------------------------------------------------
template<bool SIG_SRC, bool SIG_OTH, bool DO_BCE, int CBASE>
__device__ __forceinline__
void skel_core(const float* __restrict__ src, const float* __restrict__ oth,
               double* __restrict__ acc, __half* cur, __half* nxt, float* red,
               int z, int r0, int c0, int tid, int bid)
{
    const float* s = src + (size_t)z * NPIX;

    // ---- load 88x88 region (+4-col pad), phase-aligned ----
    {   // phase A: strips 0..15, 1 row x 16 strips per quarter-wave
        const int st = tid & 15, c = 4 * st;
        const int gc = c0 - HALO + c;
        const bool vec = (gc >= 0) && (gc + 3 < W_IMG);
        for (int r = tid >> 4; r < RG; r += 32) {
            const int gr = min(max(r0 - HALO + r, 0), H_IMG - 1);
            const float* row = s + (size_t)gr * W_IMG;
            float4 v;
            if (vec) v = *(const float4*)&row[gc];
            else {
                v.x = row[min(max(gc + 0, 0), W_IMG - 1)];
                v.y = row[min(max(gc + 1, 0), W_IMG - 1)];
                v.z = row[min(max(gc + 2, 0), W_IMG - 1)];
                v.w = row[min(max(gc + 3, 0), W_IMG - 1)];
            }
            if (SIG_SRC) { v.x = sigm(v.x); v.y = sigm(v.y); v.z = sigm(v.z); v.w = sigm(v.w); }
            st4h(&cur[r * HST + c], v.x, v.y, v.z, v.w);
        }
    }
    {   // phase B: strips 16..22 (incl pad strip 22), 2 rows x 8 strips
        const int st = 16 + (tid & 7);
        if (st < 23) {
            const int c = 4 * st, gc = c0 - HALO + c;
            const bool vec = (gc >= 0) && (gc + 3 < W_IMG);
            for (int r = tid >> 3; r < RG; r += 64) {
                const int gr = min(max(r0 - HALO + r, 0), H_IMG - 1);
                const float* row = s + (size_t)gr * W_IMG;
                float4 v;
                if (vec) v = *(const float4*)&row[gc];
                else {
                    v.x = row[min(max(gc + 0, 0), W_IMG - 1)];
                    v.y = row[min(max(gc + 1, 0), W_IMG - 1)];
                    v.z = row[min(max(gc + 2, 0), W_IMG - 1)];
                    v.w = row[min(max(gc + 3, 0), W_IMG - 1)];
                }
                if (SIG_SRC) { v.x = sigm(v.x); v.y = sigm(v.y); v.z = sigm(v.z); v.w = sigm(v.w); }
                st4h(&cur[r * HST + c], v.x, v.y, v.z, v.w);
            }
        }
    }
    __syncthreads();

    const bool edge = (r0 == 0) | (c0 == 0) | (r0 == H_IMG - TILE) | (c0 == W_IMG - TILE);

    // packed skel accumulators: strips A,B x half2 pairs (01,23). f16 zero = 0.
    unsigned skA01 = 0, skA23 = 0, skB01 = 0, skB23 = 0;

    const int oy = tid >> 3;      // owned row 0..63
    const int j  = tid & 7;       // strip slot (strips j, j+8 of owned)
    const int rr = HALO + oy;

    for (int k = 0; k < 11; ++k) {
        if (edge) { band_fix_inf(cur, r0, c0, tid); __syncthreads(); }

        const int rlo = k + 1, rhi = RG - 1 - k;        // rows [rlo, rhi)
        const int sA = rlo >> 2, sE = (rhi + 3) >> 2;   // strips [sA, sE)

        // ---- erode phase A: strips sA..sA+15 (1 row x 16 strips/quarter) ----
        {
            const int l  = tid & 15;
            const int st = sA + l;
            const int c  = 4 * st;
            const int gcb = c0 - HALO + c;
            const bool cOOB = ((unsigned)gcb > (unsigned)(W_IMG - 4));
            for (int r = rlo + (tid >> 4); r < rhi; r += 32) {
                const int base = r * HST + c;
                const uint2 mid = ld2u(&cur[base]);
                const uint2 up  = ld2u(&cur[base - HST]);
                const uint2 dn  = ld2u(&cur[base + HST]);
                unsigned lfreg = (unsigned)__shfl_up((int)mid.y, 1);    // left strip m23
                unsigned rtreg = (unsigned)__shfl_down((int)mid.x, 1);  // right strip m01
                if (l == 0)  lfreg = ((unsigned)*(const unsigned short*)(cur + base - 1)) << 16;
                if (l == 15) rtreg = (unsigned)*(const unsigned short*)(cur + base + 4);
                const unsigned L01 = alignb(mid.x, lfreg);   // [m-1, m0]
                const unsigned L23 = alignb(mid.y, mid.x);   // [m1 , m2] (== R01)
                const unsigned R23 = alignb(rtreg, mid.y);   // [m3 , m4]
                unsigned e01 = pk_min(pk_min(pk_min(up.x, dn.x), mid.x), pk_min(L01, L23));
                unsigned e23 = pk_min(pk_min(pk_min(up.y, dn.y), mid.y), pk_min(L23, R23));
                if (edge) {
                    const int gr = r0 - HALO + r;
                    if (((unsigned)gr >= (unsigned)H_IMG) | cOOB) { e01 = PK_NINF; e23 = PK_NINF; }
                }
                st2u(&nxt[base], e01, e23);
            }
        }
        // ---- erode phase B: strips sA+16..sE-1 (2 rows x 8 strips/quarter) ----
        {
            const int l  = tid & 7;
            const int st = sA + 16 + l;
            if (st < sE) {   // sE-sA <= 22 -> l <= 6 active, shfl stays in-row
                const int c = 4 * st;
                const int gcb = c0 - HALO + c;
                const bool cOOB  = ((unsigned)gcb > (unsigned)(W_IMG - 4));
                const bool lastS = (st == sE - 1);
                for (int r = rlo + (tid >> 3); r < rhi; r += 64) {
                    const int base = r * HST + c;
                    const uint2 mid = ld2u(&cur[base]);
                    const uint2 up  = ld2u(&cur[base - HST]);
                    const uint2 dn  = ld2u(&cur[base + HST]);
                    unsigned lfreg = (unsigned)__shfl_up((int)mid.y, 1);
                    unsigned rtreg = (unsigned)__shfl_down((int)mid.x, 1);
                    if (l == 0)  lfreg = ((unsigned)*(const unsigned short*)(cur + base - 1)) << 16;
                    if (lastS)   rtreg = (unsigned)*(const unsigned short*)(cur + base + 4);
                    const unsigned L01 = alignb(mid.x, lfreg);
                    const unsigned L23 = alignb(mid.y, mid.x);
                    const unsigned R23 = alignb(rtreg, mid.y);
                    unsigned e01 = pk_min(pk_min(pk_min(up.x, dn.x), mid.x), pk_min(L01, L23));
                    unsigned e23 = pk_min(pk_min(pk_min(up.y, dn.y), mid.y), pk_min(L23, R23));
                    if (edge) {
                        const int gr = r0 - HALO + r;
                        if (((unsigned)gr >= (unsigned)H_IMG) | cOOB) { e01 = PK_NINF; e23 = PK_NINF; }
                    }
                    st2u(&nxt[base], e01, e23);
                }
            }
        }
        __syncthreads();

        // ---- dilate(ernew) at owned pixels + packed skel update ----
        {
            const int cA = HALO + 4 * j;           // strip j
            const int cB = cA + 32;                // strip j+8
            const int bA = rr * HST + cA;
            const int bB = rr * HST + cB;
            const uint2 a0 = ld2u(&nxt[bA - HST]);
            const uint2 m0 = ld2u(&nxt[bA]);
            const uint2 d0 = ld2u(&nxt[bA + HST]);
            const uint2 a1 = ld2u(&nxt[bB - HST]);
            const uint2 m1 = ld2u(&nxt[bB]);
            const uint2 d1 = ld2u(&nxt[bB + HST]);
            const unsigned VA01 = pk_max(pk_max(a0.x, m0.x), d0.x);
            const unsigned VA23 = pk_max(pk_max(a0.y, m0.y), d0.y);
            const unsigned VB01 = pk_max(pk_max(a1.x, m1.x), d1.x);
            const unsigned VB23 = pk_max(pk_max(a1.y, m1.y), d1.y);
            // horizontal neighbor regs (hi/lo halves used via alignb)
            unsigned vlA = (unsigned)__shfl_up((int)VA23, 1);        // high = V[cA-1]
            const unsigned vrAa = (unsigned)__shfl_down((int)VA01, 1);
            const unsigned vrAb = (unsigned)__shfl_up((int)VB01, 7); // j==7 seam: strip 8
            unsigned vrA = (j == 7) ? vrAb : vrAa;                   // low = V[cA+4]
            const unsigned vlBa = (unsigned)__shfl_up((int)VB23, 1);
            const unsigned vlBb = (unsigned)__shfl_down((int)VA23, 7); // j==0 seam: strip 7
            unsigned vlB = (j == 0) ? vlBb : vlBa;                   // high = V[cB-1]
            unsigned vrB = (unsigned)__shfl_down((int)VB01, 1);      // low = V[cB+4]
            if (j == 0) {   // block-left halo col: scalar u16 vertical max (low halves)
                const unsigned t1 = *(const unsigned short*)(nxt + bA - HST - 1);
                const unsigned t2 = *(const unsigned short*)(nxt + bA - 1);
                const unsigned t3 = *(const unsigned short*)(nxt + bA + HST - 1);
                vlA = pk_max(pk_max(t1, t2), t3) << 16;              // value -> high half
            }
            if (j == 7) {   // block-right halo col
                const unsigned t1 = *(const unsigned short*)(nxt + bB - HST + 4);
                const unsigned t2 = *(const unsigned short*)(nxt + bB + 4);
                const unsigned t3 = *(const unsigned short*)(nxt + bB + HST + 4);
                vrB = pk_max(pk_max(t1, t2), t3);                    // value in low half
            }
            // open = horizontal max3 of V (packed)
            const unsigned LA = alignb(VA01, vlA);    // [V-1, V0]
            const unsigned MA = alignb(VA23, VA01);   // [V1 , V2]
            const unsigned RA = alignb(vrA,  VA23);   // [V3 , V4]
            const unsigned oA01 = pk_max(pk_max(LA, MA), VA01);
            const unsigned oA23 = pk_max(pk_max(MA, RA), VA23);
            const unsigned LB = alignb(VB01, vlB);
            const unsigned MB = alignb(VB23, VB01);
            const unsigned RB = alignb(vrB,  VB23);
            const unsigned oB01 = pk_max(pk_max(LB, MB), VB01);
            const unsigned oB23 = pk_max(pk_max(MB, RB), VB23);
            // er_k at owned (pre-erode center values)
            const uint2 eA = ld2u(&cur[bA]);
            const uint2 eB = ld2u(&cur[bB]);
            // delta = relu(e - open); skel += relu(delta - skel*delta)
            unsigned d, u;
            d = pk_max(pk_add(eA.x, oA01 ^ PK_SGN), 0u);
            u = pk_max(pk_fma(skA01 ^ PK_SGN, d, d), 0u);
            skA01 = pk_add(skA01, u);
            d = pk_max(pk_add(eA.y, oA23 ^ PK_SGN), 0u);
            u = pk_max(pk_fma(skA23 ^ PK_SGN, d, d), 0u);
            skA23 = pk_add(skA23, u);
            d = pk_max(pk_add(eB.x, oB01 ^ PK_SGN), 0u);
            u = pk_max(pk_fma(skB01 ^ PK_SGN, d, d), 0u);
            skB01 = pk_add(skB01, u);
            d = pk_max(pk_add(eB.y, oB23 ^ PK_SGN), 0u);
            u = pk_max(pk_fma(skB23 ^ PK_SGN, d, d), 0u);
            skB23 = pk_add(skB23, u);
        }
        __syncthreads();

        __half* tp = cur; cur = nxt; nxt = tp;
    }

    // ---- unpack skel to f32 ----
    float skf[8];
    {
        H2U u; float2 f;
        u.u = skA01; f = __half22float2(u.h); skf[0] = f.x; skf[1] = f.y;
        u.u = skA23; f = __half22float2(u.h); skf[2] = f.x; skf[3] = f.y;
        u.u = skB01; f = __half22float2(u.h); skf[4] = f.x; skf[5] = f.y;
        u.u = skB23; f = __half22float2(u.h); skf[6] = f.x; skf[7] = f.y;
    }

    // ---- fused reductions over owned pixels ----
    const size_t gbase = (size_t)z * NPIX + (size_t)(r0 + oy) * W_IMG + c0;
    const float* op = oth + gbase;
    const float* pp = src + gbase;   // pred logits (DO_BCE only)
    float ss = 0.f, sso = 0.f, sb = 0.f, sp = 0.f, sy = 0.f, spy = 0.f;
    #pragma unroll
    for (int t = 0; t < 2; ++t) {
        const int cc = 4 * (j + 8 * t);
        float4 ov = *(const float4*)&op[cc];
        float o0 = ov.x, o1 = ov.y, o2 = ov.z, o3 = ov.w;
        if (SIG_OTH) { o0 = sigm(o0); o1 = sigm(o1); o2 = sigm(o2); o3 = sigm(o3); }
        const float s0 = skf[4*t], s1 = skf[4*t+1], s2 = skf[4*t+2], s3 = skf[4*t+3];
        ss  += s0 + s1 + s2 + s3;
        sso += s0 * o0 + s1 * o1 + s2 * o2 + s3 * o3;
        if (DO_BCE) {
            const float4 xv = *(const float4*)&pp[cc];
            const float xs[4] = {xv.x, xv.y, xv.z, xv.w};
            const float ys[4] = {o0, o1, o2, o3};   // SIG_OTH=false here: raw target
            #pragma unroll
            for (int q = 0; q < 4; ++q) {
                const float x = xs[q], y = ys[q];
                const float zz = __expf(-fabsf(x));
                const float inv = 1.0f / (1.0f + zz);
                sb += fmaxf(x, 0.f) + __logf(1.0f + zz) - y * x;
                const float p = (x >= 0.f) ? inv : zz * inv;
                sp += p; sy += y; spy += p * y;
            }
        }
    }
    for (int off = 32; off > 0; off >>= 1) {
        ss  += __shfl_down(ss,  off);
        sso += __shfl_down(sso, off);
        if (DO_BCE) {
            sb  += __shfl_down(sb,  off);
            sp  += __shfl_down(sp,  off);
            sy  += __shfl_down(sy,  off);
            spy += __shfl_down(spy, off);
        }
    }
    const int wid = tid >> 6, lane = tid & 63;
    if (lane == 0) {
        red[0 * 8 + wid] = ss;  red[1 * 8 + wid] = sso;
        if (DO_BCE) {
            red[2 * 8 + wid] = sb;  red[3 * 8 + wid] = sp;
            red[4 * 8 + wid] = sy;  red[5 * 8 + wid] = spy;
        }
    }
    __syncthreads();
    if (tid == 0) {
        double SS = 0, SO = 0, B0 = 0, B1 = 0, B2 = 0, B3 = 0;
        for (int w = 0; w < 8; ++w) {
            SS += (double)red[0 * 8 + w];  SO += (double)red[1 * 8 + w];
            if (DO_BCE) {
                B0 += (double)red[2 * 8 + w]; B1 += (double)red[3 * 8 + w];
                B2 += (double)red[4 * 8 + w]; B3 += (double)red[5 * 8 + w];
            }
        }
        const int slot = bid & (SLOTS - 1);
        atomicAdd(&acc[slot * 8 + CBASE],     SS);
        atomicAdd(&acc[slot * 8 + CBASE + 1], SO);
        if (DO_BCE) {
            atomicAdd(&acc[slot * 8 + 0], B0);
            atomicAdd(&acc[slot * 8 + 1], B1);
            atomicAdd(&acc[slot * 8 + 2], B2);
            atomicAdd(&acc[slot * 8 + 3], B3);
        }
    }
}

// ---------------------------------------------------------------------------
// Bool path (z>=16): EXACT bit-packed skeleton of the binary target.
// Region 88x88 bits; thread t<352 owns word w=t&3 (w<3 data) of row r=t>>2.
// Bit b of word w = region col 32w+b. Erode = AND over plus (funnel shifts +
// LDS vertical), dilate = OR over 3x3, skel |= er & ~open. Out-of-image cells:
// OR-in mask (=1, erode identity) on read; AND-out (=0, dilate identity) on
// erode output. Garbage at region margins confined exactly as in f16 path
// (erode-k output trusted at margin >= k+1; dilate ring needs margin 11).
// One barrier per iteration (ping-pong buffers, disjoint read/write sets).
// ---------------------------------------------------------------------------
__device__ __forceinline__
void bool_core(const float* __restrict__ tgt, const float* __restrict__ pred,
               double* __restrict__ acc, unsigned* bb, float* red,
               int z, int r0, int c0, int tid, int bid)
{
    unsigned* A  = bb;              // [RG*4]
    unsigned* B  = bb + RG * 4;
    unsigned* SK = bb + RG * 8;
    const float* tz = tgt + (size_t)z * NPIX;

    // ---- load + pack bits via wave ballot (row-major, 64+24 cols) ----
    {
        const int wv = tid >> 6, ln = tid & 63;
        for (int r = wv; r < RG; r += 8) {
            const int gr = min(max(r0 - HALO + r, 0), H_IMG - 1);
            const float* row = tz + (size_t)gr * W_IMG;
            const int gc = c0 - HALO + ln;
            const float v = row[min(max(gc, 0), W_IMG - 1)];
            const unsigned long long b0 = __ballot(v > 0.5f);
            float v2 = 0.f;
            if (ln < 24) v2 = row[min(max(gc + 64, 0), W_IMG - 1)];
            const unsigned long long b1 = __ballot((ln < 24) && (v2 > 0.5f));
            if (ln < 4) {
                const unsigned val = (ln == 0) ? (unsigned)b0
                                   : (ln == 1) ? (unsigned)(b0 >> 32)
                                   : (ln == 2) ? (unsigned)b1 : 0u;
                A[r * 4 + ln] = val;
            }
        }
    }
    __syncthreads();

    const int r = tid >> 2, w = tid & 3;
    const bool act = (tid < RG * 4);

    // out-of-image masks (1 = outside image)
    const int gcb = c0 - HALO + 32 * w;
    unsigned cm = 0;
    {
        const int lo = -gcb;                 // bits [0,lo) have gc<0
        if (lo > 0) cm |= (lo >= 32) ? 0xFFFFFFFFu : ((1u << lo) - 1u);
        const int hs = W_IMG - gcb;          // bits >= hs have gc>=W
        if (hs < 32) cm |= (hs <= 0) ? 0xFFFFFFFFu : ~((1u << hs) - 1u);
    }
    const int grs = r0 - HALO + r;
    const unsigned Mself = cm | ((((unsigned)grs)       >= (unsigned)H_IMG) ? 0xFFFFFFFFu : 0u);
    const unsigned Mup   = cm | ((((unsigned)(grs - 1)) >= (unsigned)H_IMG) ? 0xFFFFFFFFu : 0u);
    const unsigned Mdn   = cm | ((((unsigned)(grs + 1)) >= (unsigned)H_IMG) ? 0xFFFFFFFFu : 0u);
    const unsigned KILL  = ~Mself;

    const int iu = max(r - 1, 0) * 4 + w;
    const int id = min(r + 1, RG - 1) * 4 + w;

    unsigned mid  = act ? A[r * 4 + w] : 0u;
    unsigned skel = 0u;
    unsigned* sB = A; unsigned* dB = B;

    for (int k = 0; k < 11; ++k) {
        // erode (AND over plus shape)
        const unsigned me = mid | Mself;
        unsigned up = 0xFFFFFFFFu, dn = 0xFFFFFFFFu;
        if (act) { up = sB[iu] | Mup; dn = sB[id] | Mdn; }
        const unsigned pv = (unsigned)__shfl_up((int)me, 1);    // word w-1 (garbage at w==0: margin-0 col)
        const unsigned nx = (unsigned)__shfl_down((int)me, 1);  // word w+1
        const unsigned Lh = (me << 1) | (pv >> 31);
        const unsigned Rh = (me >> 1) | (nx << 31);
        const unsigned e  = (me & up & dn & Lh & Rh) & KILL;
        if (act) dB[r * 4 + w] = e;
        __syncthreads();
        // dilate (OR over 3x3) + skel |= er & ~open
        unsigned eu = 0, ed = 0;
        if (act) { eu = dB[iu]; ed = dB[id]; }
        const unsigned V  = e | eu | ed;
        const unsigned pV = (unsigned)__shfl_up((int)V, 1);
        const unsigned nV = (unsigned)__shfl_down((int)V, 1);
        const unsigned open = V | ((V << 1) | (pV >> 31)) | ((V >> 1) | (nV << 31));
        skel |= mid & ~open;
        mid = e;
        unsigned* tp = sB; sB = dB; dB = tp;
    }
    if (act) SK[r * 4 + w] = skel;
    __syncthreads();

    // ---- epilogue: ss = sum(skel bits), sso = sum(skel * sigmoid(pred)) ----
    const int oy = tid >> 3, j = tid & 7;
    const size_t gbase = (size_t)z * NPIX + (size_t)(r0 + oy) * W_IMG + c0;
    const float* pp = pred + gbase;
    float ss = 0.f, sso = 0.f;
    #pragma unroll
    for (int t = 0; t < 2; ++t) {
        const int cc  = 4 * (j + 8 * t);      // owned col offset (strip base)
        const int rcb = HALO + cc;            // region col (4-aligned, no word straddle)
        const unsigned wd = SK[(HALO + oy) * 4 + (rcb >> 5)] >> (rcb & 31);
        const float4 xv = *(const float4*)&pp[cc];
        const float p0 = sigm(xv.x), p1 = sigm(xv.y), p2 = sigm(xv.z), p3 = sigm(xv.w);
        const float b0 = (float)( wd       & 1u);
        const float b1 = (float)((wd >> 1) & 1u);
        const float b2 = (float)((wd >> 2) & 1u);
        const float b3 = (float)((wd >> 3) & 1u);
        ss  += b0 + b1 + b2 + b3;
        sso += b0 * p0 + b1 * p1 + b2 * p2 + b3 * p3;
    }
    for (int off = 32; off > 0; off >>= 1) {
        ss  += __shfl_down(ss,  off);
        sso += __shfl_down(sso, off);
    }
    const int wid = tid >> 6, lane = tid & 63;
    if (lane == 0) { red[0 * 8 + wid] = ss; red[1 * 8 + wid] = sso; }
    __syncthreads();
    if (tid == 0) {
        double SS = 0, SO = 0;
        for (int wq = 0; wq < 8; ++wq) { SS += (double)red[0 * 8 + wq]; SO += (double)red[1 * 8 + wq]; }
        const int slot = bid & (SLOTS - 1);
        atomicAdd(&acc[slot * 8 + 6], SS);
        atomicAdd(&acc[slot * 8 + 7], SO);
    }
}

// Both skeletons in one dispatch: z<16 -> f16 skel(sigmoid(pred)) + BCE/dice;
// z>=16 -> exact bit-packed skel(target), reduced against sigmoid(pred).
__global__ __launch_bounds__(512, 8)
void skel_all(const float* __restrict__ pred, const float* __restrict__ tgt,
              double* __restrict__ acc)
{
    __shared__ __align__(16) __half buf0[RG * HST];
    __shared__ __align__(16) __half buf1[RG * HST];
    __shared__ float red[48];
    const int tid = threadIdx.x;
    const int r0 = blockIdx.y * TILE, c0 = blockIdx.x * TILE;
    const int bid = ((int)blockIdx.z & 15) * 256 + blockIdx.y * 16 + blockIdx.x;
    if ((int)blockIdx.z < N_B)
        skel_core<true, false, true, 4>(pred, tgt, acc, buf0, buf1, red,
                                        blockIdx.z, r0, c0, tid, bid);
    else
        bool_core(tgt, pred, acc, (unsigned*)buf0, red,
                  (int)blockIdx.z - N_B, r0, c0, tid, bid);
}

__global__ void zero_acc(double* acc) { acc[threadIdx.x] = 0.0; }

__global__ void finalize_k(const double* __restrict__ acc, float* __restrict__ out)
{
    __shared__ double S[8];
    const int jj = threadIdx.x;
    if (jj < 8) {
        double t = 0.0;
        for (int s = 0; s < SLOTS; ++s) t += acc[s * 8 + jj];
        S[jj] = t;
    }
    __syncthreads();
    if (jj == 0) {
        const double bce   = S[0] / (double)N_TOT;
        const double dice  = (2.0 * S[3] + 1.0) / (S[1] + S[2] + 1.0);
        const double tprec = (S[5] + 1.0) / (S[4] + 1.0);
        const double tsens = (S[7] + 1.0) / (S[6] + 1.0);
        const double cl    = 2.0 * tprec * tsens / (tprec + tsens + 1e-7);
        out[0] = (float)(0.3 * bce + 0.3 * (1.0 - dice) + 0.4 * (1.0 - cl));
    }
}

// ---------------------------------------------------------------------------
extern "C" void kernel_launch(void* const* d_in, const int* in_sizes, int n_in,
                              void* d_out, int out_size, void* d_ws, size_t ws_size,
                              hipStream_t stream)
{
    const float* pred = (const float*)d_in[0];
    const float* tgt  = (const float*)d_in[1];
    float* out = (float*)d_out;
    double* acc = (double*)d_ws;                  // SLOTS*8 doubles = 2 KB

    zero_acc<<<1, SLOTS * 8, 0, stream>>>(acc);

    const dim3 grid(W_IMG / TILE, H_IMG / TILE, 2 * N_B);   // (16,16,32)
    skel_all<<<grid, 512, 0, stream>>>(pred, tgt, acc);

    finalize_k<<<1, 64, 0, stream>>>(acc, out);
}